// Round 5
// baseline (517.182 us; speedup 1.0000x reference)
//
#include <hip/hip_runtime.h>
#include <stdint.h>

#define B_    2
#define T_    2048
#define NH_   16
#define NKV_  4
#define HD_   128
#define RANK_ 512
#define DIM_  2048
#define BT_   (B_*T_)
#define EPS_  1.1920928955078125e-07f
#define LOG2E_ 1.4426950408889634f

typedef __bf16 bf16x8 __attribute__((ext_vector_type(8)));
typedef float  f32x4  __attribute__((ext_vector_type(4)));

__device__ inline unsigned short f2bf(float f) {
    unsigned int u = __float_as_uint(f);
    u += 0x7fff + ((u >> 16) & 1);   // round-to-nearest-even
    return (unsigned short)(u >> 16);
}
__device__ inline float bf2f(unsigned short u) {
    return __uint_as_float(((unsigned int)u) << 16);
}
// exp2: hardware v_exp_f32 (avoid __exp2f: glibc macro clash on this toolchain)
__device__ inline float fast_exp2(float x) { return __builtin_amdgcn_exp2f(x); }

#define GLOAD_LDS16(gp, lp)                                                        \
    __builtin_amdgcn_global_load_lds(                                              \
        (const __attribute__((address_space(1))) void*)(gp),                       \
        (__attribute__((address_space(3))) void*)(lp), 16, 0, 0)

// ---------------------------------------------------------------- batched f32 -> bf16 (one launch)
struct CvtArgs {
    const float* src[6];
    unsigned short* dst[6];
    int start4[6];   // cumulative float4 offsets
};
__global__ __launch_bounds__(256) void cvt_all(CvtArgs a, int total4) {
    int i = blockIdx.x * 256 + threadIdx.x;
    if (i >= total4) return;
    int s = 0;
#pragma unroll
    for (int k = 1; k < 6; k++) s += (i >= a.start4[k]) ? 1 : 0;
    int j = i - a.start4[s];
    float4 v = ((const float4*)a.src[s])[j];
    ushort4 o;
    o.x = f2bf(v.x); o.y = f2bf(v.y); o.z = f2bf(v.z); o.w = f2bf(v.w);
    ((ushort4*)a.dst[s])[j] = o;
}

// ---------------------------------------------------------------- GEMM C = A * W^T  (m97 recipe)
__device__ inline void store_out(float* p, float v) { *p = v; }
__device__ inline void store_out(unsigned short* p, float v) { *p = f2bf(v); }

template <typename OT>
__global__ __launch_bounds__(256) void gemm_bt(const unsigned short* __restrict__ A,
                                               const unsigned short* __restrict__ W,
                                               OT* __restrict__ C,
                                               int M, int N, int K) {
    __shared__ unsigned short As[128][32];
    __shared__ unsigned short Ws[128][32];
    int tid  = threadIdx.x;
    int lane = tid & 63, wave = tid >> 6;
    int quad = lane >> 4, l16 = lane & 15;
    int wm = (wave >> 1) * 64, wn = (wave & 1) * 64;
    long m0 = (long)blockIdx.y * 128, n0 = (long)blockIdx.x * 128;

    int sr = wave * 32 + (lane >> 2);
    int scl = (lane & 3) * 8;
    const unsigned short* Ag0 = A + (m0 + sr) * K + scl;
    const unsigned short* Ag1 = A + (m0 + sr + 16) * K + scl;
    const unsigned short* Wg0 = W + (n0 + sr) * K + scl;
    const unsigned short* Wg1 = W + (n0 + sr + 16) * K + scl;
    unsigned short* Al0 = &As[wave * 32][0];
    unsigned short* Al1 = &As[wave * 32 + 16][0];
    unsigned short* Wl0 = &Ws[wave * 32][0];
    unsigned short* Wl1 = &Ws[wave * 32 + 16][0];

    f32x4 acc[4][4];
#pragma unroll
    for (int i = 0; i < 4; i++)
#pragma unroll
        for (int j = 0; j < 4; j++) acc[i][j] = (f32x4){0.f, 0.f, 0.f, 0.f};

    for (int k0 = 0; k0 < K; k0 += 32) {
        __syncthreads();
        GLOAD_LDS16(Ag0 + k0, Al0);
        GLOAD_LDS16(Ag1 + k0, Al1);
        GLOAD_LDS16(Wg0 + k0, Wl0);
        GLOAD_LDS16(Wg1 + k0, Wl1);
        __syncthreads();
        bf16x8 af[4], wf[4];
#pragma unroll
        for (int i = 0; i < 4; i++) af[i] = *(const bf16x8*)&As[wm + i * 16 + l16][quad * 8];
#pragma unroll
        for (int j = 0; j < 4; j++) wf[j] = *(const bf16x8*)&Ws[wn + j * 16 + l16][quad * 8];
#pragma unroll
        for (int i = 0; i < 4; i++)
#pragma unroll
            for (int j = 0; j < 4; j++)
                acc[i][j] = __builtin_amdgcn_mfma_f32_16x16x32_bf16(af[i], wf[j], acc[i][j], 0, 0, 0);
    }
#pragma unroll
    for (int i = 0; i < 4; i++)
#pragma unroll
        for (int j = 0; j < 4; j++)
#pragma unroll
            for (int r = 0; r < 4; r++) {
                long row = m0 + wm + i * 16 + quad * 4 + r;
                long col = n0 + wn + j * 16 + l16;
                store_out(&C[row * N + col], acc[i][j][r]);
            }
}

// GEMM with split destination: block-columns < N1 -> C1 (ld N1), else C2 (ld N-N1). Both bf16.
__global__ __launch_bounds__(256) void gemm_split(const unsigned short* __restrict__ A,
                                                  const unsigned short* __restrict__ W,
                                                  unsigned short* __restrict__ C1, int N1,
                                                  unsigned short* __restrict__ C2,
                                                  int M, int N, int K) {
    __shared__ unsigned short As[128][32];
    __shared__ unsigned short Ws[128][32];
    int tid  = threadIdx.x;
    int lane = tid & 63, wave = tid >> 6;
    int quad = lane >> 4, l16 = lane & 15;
    int wm = (wave >> 1) * 64, wn = (wave & 1) * 64;
    long m0 = (long)blockIdx.y * 128, n0 = (long)blockIdx.x * 128;

    int sr = wave * 32 + (lane >> 2);
    int scl = (lane & 3) * 8;
    const unsigned short* Ag0 = A + (m0 + sr) * K + scl;
    const unsigned short* Ag1 = A + (m0 + sr + 16) * K + scl;
    const unsigned short* Wg0 = W + (n0 + sr) * K + scl;
    const unsigned short* Wg1 = W + (n0 + sr + 16) * K + scl;
    unsigned short* Al0 = &As[wave * 32][0];
    unsigned short* Al1 = &As[wave * 32 + 16][0];
    unsigned short* Wl0 = &Ws[wave * 32][0];
    unsigned short* Wl1 = &Ws[wave * 32 + 16][0];

    f32x4 acc[4][4];
#pragma unroll
    for (int i = 0; i < 4; i++)
#pragma unroll
        for (int j = 0; j < 4; j++) acc[i][j] = (f32x4){0.f, 0.f, 0.f, 0.f};

    for (int k0 = 0; k0 < K; k0 += 32) {
        __syncthreads();
        GLOAD_LDS16(Ag0 + k0, Al0);
        GLOAD_LDS16(Ag1 + k0, Al1);
        GLOAD_LDS16(Wg0 + k0, Wl0);
        GLOAD_LDS16(Wg1 + k0, Wl1);
        __syncthreads();
        bf16x8 af[4], wf[4];
#pragma unroll
        for (int i = 0; i < 4; i++) af[i] = *(const bf16x8*)&As[wm + i * 16 + l16][quad * 8];
#pragma unroll
        for (int j = 0; j < 4; j++) wf[j] = *(const bf16x8*)&Ws[wn + j * 16 + l16][quad * 8];
#pragma unroll
        for (int i = 0; i < 4; i++)
#pragma unroll
            for (int j = 0; j < 4; j++)
                acc[i][j] = __builtin_amdgcn_mfma_f32_16x16x32_bf16(af[i], wf[j], acc[i][j], 0, 0, 0);
    }
    unsigned short* Cb;
    long ldc, nb;
    if (n0 < N1) { Cb = C1; ldc = N1;     nb = n0; }
    else         { Cb = C2; ldc = N - N1; nb = n0 - N1; }
#pragma unroll
    for (int i = 0; i < 4; i++)
#pragma unroll
        for (int j = 0; j < 4; j++)
#pragma unroll
            for (int r = 0; r < 4; r++) {
                long row = m0 + wm + i * 16 + quad * 4 + r;
                long col = nb + wn + j * 16 + l16;
                Cb[row * ldc + col] = f2bf(acc[i][j][r]);
            }
}

// ---------------------------------------------------------------- RMS-norm + RoPE (+gain), bf16 in
// Q path folds gain * 1/sqrt(128) * log2(e)  (attention runs in exp2 domain)
template <int NHEADS, bool GAIN>
__global__ __launch_bounds__(256) void qk_prep(const unsigned short* __restrict__ lin,
                                               const float* __restrict__ gain,
                                               unsigned short* __restrict__ out,
                                               int incols) {
    int r    = blockIdx.x * 4 + (threadIdx.x >> 6);
    int lane = threadIdx.x & 63;
    int bt = r / NHEADS, h = r % NHEADS;
    const unsigned short* ip = lin + (long)bt * incols + h * 128;
    float x1 = bf2f(ip[lane]), x2 = bf2f(ip[lane + 64]);
    float ss = x1 * x1 + x2 * x2;
#pragma unroll
    for (int off = 32; off; off >>= 1) ss += __shfl_xor(ss, off);
    float inv = rsqrtf(ss * (1.0f / 128.0f) + EPS_);
    x1 *= inv; x2 *= inv;
    int b = bt / T_, t = bt % T_;
    float freq = expf(-(float)lane * 0.14391156463f);   // ln(10000)/64
    float f = (float)t * freq;
    float s, c;
    sincosf(f, &s, &c);
    float g = GAIN ? gain[h] * 0.08838834764831845f * LOG2E_ : 1.0f;
    float o1 = (x1 * c + x2 * s) * g;
    float o2 = (x2 * c - x1 * s) * g;
    unsigned short* op = out + ((long)(b * NHEADS + h) * T_ + t) * 128;
    op[lane]      = f2bf(o1);
    op[lane + 64] = f2bf(o2);
}

// ---------------------------------------------------------------- V transpose: kv_lin cols 512..1023 (bf16) -> (B,NKV,128,T) bf16
__global__ __launch_bounds__(256) void v_transpose(const unsigned short* __restrict__ vlin,
                                                   unsigned short* __restrict__ vt) {
    __shared__ unsigned short tile[32][33];
    int bkv = blockIdx.z, b = bkv >> 2, kv = bkv & 3;
    int t0 = blockIdx.x * 32, d0 = blockIdx.y * 32;
    int tx = threadIdx.x & 31, ty = threadIdx.x >> 5;
#pragma unroll
    for (int rr = 0; rr < 32; rr += 8) {
        int t = t0 + ty + rr;
        tile[ty + rr][tx] = vlin[((long)(b * T_ + t)) * 1024 + 512 + kv * 128 + d0 + tx];
    }
    __syncthreads();
#pragma unroll
    for (int rr = 0; rr < 32; rr += 8) {
        int d = d0 + ty + rr;
        vt[((long)((b * NKV_ + kv) * 128 + d)) * T_ + t0 + tx] = tile[tx][ty + rr];
    }
}

// ---------------------------------------------------------------- flash attention
// Block = (b,kv,h',qb,c). XCD swizzle: blockIdx%8 = (b*4+kv) so the 160 blocks sharing one
// K/V pair (2 MB) live on one XCD's L2. 4 waves x 32 q rows; kv chunk = up to 8x64 tiles.
// LDS: Vs2 16KB persistent + KsPt 18KB (K tile during QK, P^T bounce during softmax/PV)
// -> 34KB -> 4 blocks/CU. Extra barrier between QK-reads and P-writes makes overlay safe.
// exp2 domain (log2e folded into Q scale).
__global__ __launch_bounds__(256, 4) void attn_kernel(const unsigned short* __restrict__ Q,
                                                      const unsigned short* __restrict__ Km,
                                                      const unsigned short* __restrict__ Vt,
                                                      unsigned short* __restrict__ po,
                                                      float* __restrict__ pm,
                                                      float* __restrict__ pl) {
    __shared__ alignas(16) unsigned short Vs2[2][128][32];   // [kv-chunk][d][kv in chunk]
    __shared__ alignas(16) unsigned short KsPt[4 * 32 * 72]; // K: [4][64][32] / P^T: [4][32][72]

    int tid = threadIdx.x, lane = tid & 63, wave = tid >> 6;
    int quad = lane >> 4, l16 = lane & 15;

    int g8 = blockIdx.x & 7;          // XCD slot = (b*4+kv)
    int j5 = blockIdx.x >> 3;         // 0..159 within the kv-group
    int hh = j5 / 40;                 // head within kv group
    int rem = j5 % 40;
    int b = g8 >> 2, kvh = g8 & 3, h = kvh * 4 + hh, bh = b * 16 + h;
    int g, loc;
    if      (rem <  4) { g = 0; loc = rem;      }
    else if (rem < 12) { g = 1; loc = rem - 4;  }
    else if (rem < 24) { g = 2; loc = rem - 12; }
    else               { g = 3; loc = rem - 24; }
    int qb = g * 4 + loc / (g + 1);
    int c  = loc % (g + 1);
    int Q0 = qb * 128 + wave * 32;

    int kt0 = c * 8;
    int nt  = min(8, 2 * qb + 2 - kt0);

    const unsigned short* qp = Q + ((long)(b * NH_ + h) * T_ + Q0) * 128;
    const char* kb = (const char*)(Km + (long)(b * NKV_ + kvh) * T_ * 128);
    const char* vb = (const char*)(Vt + (long)(b * NKV_ + kvh) * 128 * (long)T_);
    char* ksB = (char*)&KsPt[0];
    char* vsB = (char*)&Vs2[0][0][0];
    unsigned short* PtW = &KsPt[wave * 2304];   // [32][72] per wave

    bf16x8 Qf[2][4];
#pragma unroll
    for (int u = 0; u < 2; u++)
#pragma unroll
        for (int s = 0; s < 4; s++)
            Qf[u][s] = *(const bf16x8*)&qp[(u * 16 + l16) * 128 + s * 32 + quad * 8];

    f32x4 Ot[8][2];
#pragma unroll
    for (int n = 0; n < 8; n++)
#pragma unroll
        for (int u = 0; u < 2; u++) Ot[n][u] = (f32x4){0.f, 0.f, 0.f, 0.f};
    float mr[2] = {-3.0e38f, -3.0e38f}, ls[2] = {0.f, 0.f};

    for (int kt = kt0; kt < kt0 + nt; kt++) {
        int tb = kt * 64;
        __syncthreads();   // (1) prior tile's P/V reads done before restaging
        {   // stage K: wave = d-chunk s
            const char* kg = kb + (long)tb * 256 + wave * 64 + (lane >> 2) * 256 + (lane & 3) * 16;
            char* kl = ksB + wave * 4096 + lane * 16;
#pragma unroll
            for (int r = 0; r < 4; r++)
                GLOAD_LDS16(kg + r * 4096, kl + r * 1024);
        }
        {   // stage V
            int h2 = wave >> 1;
            int D0 = (wave & 1) * 64;
#pragma unroll
            for (int r = 0; r < 4; r++) {
                int D = D0 + r * 16;
                const char* vgr = vb + (long)(D + (lane >> 2)) * 4096 + (long)tb * 2 + h2 * 64 + (lane & 3) * 16;
                char* vl = vsB + h2 * 8192 + D * 64 + lane * 16;
                GLOAD_LDS16(vgr, vl);
            }
        }
        __syncthreads();   // (2) staged data visible

        f32x4 sc[4][2];
#pragma unroll
        for (int j = 0; j < 4; j++)
#pragma unroll
            for (int u = 0; u < 2; u++) sc[j][u] = (f32x4){0.f, 0.f, 0.f, 0.f};
#pragma unroll
        for (int j = 0; j < 4; j++)
#pragma unroll
            for (int s = 0; s < 4; s++) {
                bf16x8 kf = *(const bf16x8*)&KsPt[s * 2048 + (j * 16 + l16) * 32 + quad * 8];
                sc[j][0] = __builtin_amdgcn_mfma_f32_16x16x32_bf16(kf, Qf[0][s], sc[j][0], 0, 0, 0);
                sc[j][1] = __builtin_amdgcn_mfma_f32_16x16x32_bf16(kf, Qf[1][s], sc[j][1], 0, 0, 0);
            }
        __syncthreads();   // (3) all QK reads of K done; KsPt becomes P^T bounce

#pragma unroll
        for (int u = 0; u < 2; u++) {
            if (tb + 63 > Q0 + u * 16) {            // boundary tile (wave-uniform branch)
                int qg = Q0 + u * 16 + l16;
#pragma unroll
                for (int j = 0; j < 4; j++)
#pragma unroll
                    for (int r = 0; r < 4; r++) {
                        int kvg = tb + j * 16 + quad * 4 + r;
                        if (kvg > qg) sc[j][u][r] = -3.0e38f;
                    }
            }
            float mx = -3.0e38f;
#pragma unroll
            for (int j = 0; j < 4; j++)
#pragma unroll
                for (int r = 0; r < 4; r++) mx = fmaxf(mx, sc[j][u][r]);
            mx = fmaxf(mx, __shfl_xor(mx, 16));
            mx = fmaxf(mx, __shfl_xor(mx, 32));
            float mnew  = fmaxf(mr[u], mx);
            float alpha = fast_exp2(mr[u] - mnew);
            float ps = 0.f;
#pragma unroll
            for (int j = 0; j < 4; j++) {
                ushort4 pk;
                float p0 = fast_exp2(sc[j][u][0] - mnew);
                float p1 = fast_exp2(sc[j][u][1] - mnew);
                float p2 = fast_exp2(sc[j][u][2] - mnew);
                float p3 = fast_exp2(sc[j][u][3] - mnew);
                ps += (p0 + p1) + (p2 + p3);
                pk.x = f2bf(p0); pk.y = f2bf(p1); pk.z = f2bf(p2); pk.w = f2bf(p3);
                *(ushort4*)&PtW[(u * 16 + l16) * 72 + j * 16 + quad * 4] = pk;
            }
            ps += __shfl_xor(ps, 16);
            ps += __shfl_xor(ps, 32);
            ls[u] = ls[u] * alpha + ps;
            mr[u] = mnew;
#pragma unroll
            for (int n = 0; n < 8; n++) Ot[n][u] *= alpha;
        }
        __threadfence_block();   // wave-private P^T writes -> reads

#pragma unroll
        for (int h2 = 0; h2 < 2; h2++) {
            bf16x8 pf0 = *(const bf16x8*)&PtW[(0 * 16 + l16) * 72 + h2 * 32 + quad * 8];
            bf16x8 pf1 = *(const bf16x8*)&PtW[(1 * 16 + l16) * 72 + h2 * 32 + quad * 8];
#pragma unroll
            for (int n = 0; n < 8; n++) {
                bf16x8 vf = *(const bf16x8*)&Vs2[h2][n * 16 + l16][quad * 8];
                Ot[n][0] = __builtin_amdgcn_mfma_f32_16x16x32_bf16(vf, pf0, Ot[n][0], 0, 0, 0);
                Ot[n][1] = __builtin_amdgcn_mfma_f32_16x16x32_bf16(vf, pf1, Ot[n][1], 0, 0, 0);
            }
        }
    }

    // epilogue: transpose O^T -> O rows via own wave's PtW slice, 16B stores
    int i2 = qb * 4 + wave;
    long slot = (long)bh * 160 + 8 * g * (g + 1) + (long)(i2 & 15) * (g + 1) + c;
#pragma unroll
    for (int half = 0; half < 2; half++) {
        __threadfence_block();
#pragma unroll
        for (int n2 = 0; n2 < 4; n2++) {
            int n = half * 4 + n2;
#pragma unroll
            for (int u = 0; u < 2; u++) {
                ushort4 pk;
                pk.x = f2bf(Ot[n][u][0]); pk.y = f2bf(Ot[n][u][1]);
                pk.z = f2bf(Ot[n][u][2]); pk.w = f2bf(Ot[n][u][3]);
                *(ushort4*)&PtW[(u * 16 + l16) * 72 + n2 * 16 + quad * 4] = pk;
            }
        }
        __threadfence_block();
#pragma unroll
        for (int rr = 0; rr < 4; rr++) {
            int qrow = rr * 8 + (lane >> 3);
            int colseg = (lane & 7) * 8;
            uint4 val = *(const uint4*)&PtW[qrow * 72 + colseg];
            *(uint4*)&po[slot * 4096 + qrow * 128 + half * 64 + colseg] = val;
        }
    }
    if (lane < 16) {
        pm[slot * 32 + lane]      = mr[0];
        pm[slot * 32 + 16 + lane] = mr[1];
        pl[slot * 32 + lane]      = ls[0];
        pl[slot * 32 + 16 + lane] = ls[1];
    }
}

// ---------------------------------------------------------------- split-K combine -> Y (B,T,DIM) bf16
__global__ __launch_bounds__(256) void attn_combine(const unsigned short* __restrict__ po,
                                                    const float* __restrict__ pm,
                                                    const float* __restrict__ pl,
                                                    unsigned short* __restrict__ Y) {
    int bh = blockIdx.x >> 6, i2 = blockIdx.x & 63;
    int g = i2 >> 4, nc = g + 1;
    long slot0 = (long)bh * 160 + 8 * g * (g + 1) + (long)(i2 & 15) * nc;
    int col = threadIdx.x & 127;
    int r0  = threadIdx.x >> 7;
    int b = bh >> 4, h = bh & 15;
    for (int r = r0; r < 32; r += 2) {
        float M = -3.0e38f;
        for (int c = 0; c < nc; c++) M = fmaxf(M, pm[(slot0 + c) * 32 + r]);
        float L = 0.f, acc = 0.f;
        for (int c = 0; c < nc; c++) {
            float w = fast_exp2(pm[(slot0 + c) * 32 + r] - M);
            L   += pl[(slot0 + c) * 32 + r] * w;
            acc += w * bf2f(po[(slot0 + c) * 4096 + r * 128 + col]);
        }
        Y[((long)b * T_ + i2 * 32 + r) * DIM_ + h * 128 + col] = f2bf(acc / L);
    }
}

// ---------------------------------------------------------------- launch
extern "C" void kernel_launch(void* const* d_in, const int* in_sizes, int n_in,
                              void* d_out, int out_size, void* d_ws, size_t ws_size,
                              hipStream_t stream) {
    const float* x     = (const float*)d_in[0];
    const float* Wq    = (const float*)d_in[1];
    const float* Wdown = (const float*)d_in[2];
    const float* Wkup  = (const float*)d_in[3];
    const float* Wvup  = (const float*)d_in[4];
    const float* Wproj = (const float*)d_in[5];
    const float* qgain = (const float*)d_in[6];

    char* ws = (char*)d_ws;
    size_t off = 0;
    auto alloc = [&](size_t bytes) -> void* {
        void* p = ws + off;
        off += (bytes + 255) & ~(size_t)255;
        return p;
    };
    // region 1: live through the whole pipeline
    unsigned short* Wp_bf  = (unsigned short*)alloc((size_t)DIM_ * DIM_ * 2);
    unsigned short* q_bf   = (unsigned short*)alloc((size_t)BT_ * DIM_ * 2);
    unsigned short* k_bf   = (unsigned short*)alloc((size_t)B_ * NKV_ * T_ * 128 * 2);
    unsigned short* vT_bf  = (unsigned short*)alloc((size_t)B_ * NKV_ * T_ * 128 * 2);
    unsigned short* y_bf   = (unsigned short*)alloc((size_t)BT_ * DIM_ * 2);
    // region 2: dead before attn -> overlaid by split-K partials
    char* region2 = ws + off;
    unsigned short* x_bf   = (unsigned short*)alloc((size_t)BT_ * DIM_ * 2);
    unsigned short* Wqd_bf = (unsigned short*)alloc((size_t)2560 * DIM_ * 2);   // [Wq;Wdown]
    unsigned short* Wkv_bf = (unsigned short*)alloc((size_t)1024 * RANK_ * 2);  // [Wkup;Wvup]
    unsigned short* q_lin  = (unsigned short*)alloc((size_t)BT_ * DIM_ * 2);
    unsigned short* lat_bf = (unsigned short*)alloc((size_t)BT_ * RANK_ * 2);
    unsigned short* kv_lin = (unsigned short*)alloc((size_t)BT_ * 1024 * 2);

    unsigned short* po = (unsigned short*)region2;                     // 5120*4096*2 = 41.9 MB
    float* pm = (float*)(region2 + (size_t)5120 * 4096 * 2);           // 0.65 MB
    float* pl = pm + 5120 * 32;                                        // 0.65 MB

    // one batched cvt launch for all six f32->bf16 casts
    CvtArgs ca;
    ca.src[0] = x;     ca.dst[0] = x_bf;
    ca.src[1] = Wq;    ca.dst[1] = Wqd_bf;
    ca.src[2] = Wdown; ca.dst[2] = Wqd_bf + (size_t)DIM_ * DIM_;
    ca.src[3] = Wkup;  ca.dst[3] = Wkv_bf;
    ca.src[4] = Wvup;  ca.dst[4] = Wkv_bf + (size_t)512 * RANK_;
    ca.src[5] = Wproj; ca.dst[5] = Wp_bf;
    int n4[6] = {BT_ * DIM_ / 4, DIM_ * DIM_ / 4, RANK_ * DIM_ / 4,
                 512 * RANK_ / 4, 512 * RANK_ / 4, DIM_ * DIM_ / 4};
    int acc4 = 0;
    for (int i = 0; i < 6; i++) { ca.start4[i] = acc4; acc4 += n4[i]; }
    cvt_all<<<(acc4 + 255) / 256, 256, 0, stream>>>(ca, acc4);

    // fused [q_lin | lat] = x @ [Wq;Wdown]^T
    gemm_split<<<dim3(2560 / 128, BT_ / 128), 256, 0, stream>>>(x_bf, Wqd_bf, q_lin, DIM_, lat_bf, BT_, 2560, DIM_);
    // kv_lin = lat @ [Wkup;Wvup]^T
    gemm_bt<unsigned short><<<dim3(1024 / 128, BT_ / 128), 256, 0, stream>>>(lat_bf, Wkv_bf, kv_lin, BT_, 1024, RANK_);

    qk_prep<NH_, true><<<BT_ * NH_ / 4, 256, 0, stream>>>(q_lin, qgain, q_bf, DIM_);
    qk_prep<NKV_, false><<<BT_ * NKV_ / 4, 256, 0, stream>>>(kv_lin, qgain, k_bf, 1024);
    v_transpose<<<dim3(T_ / 32, 128 / 32, B_ * NKV_), 256, 0, stream>>>(kv_lin, vT_bf);

    attn_kernel<<<dim3(32 * 40), 256, 0, stream>>>(q_bf, k_bf, vT_bf, po, pm, pl);
    attn_combine<<<dim3(32 * 64), 256, 0, stream>>>(po, pm, pl, y_bf);

    gemm_bt<float><<<dim3(DIM_ / 128, BT_ / 128), 256, 0, stream>>>(y_bf, Wp_bf, (float*)d_out, BT_, DIM_, DIM_);
}

// Round 6
// 406.390 us; speedup vs baseline: 1.2726x; 1.2726x over previous
//
#include <hip/hip_runtime.h>
#include <stdint.h>

#define B_    2
#define T_    2048
#define NH_   16
#define NKV_  4
#define HD_   128
#define RANK_ 512
#define DIM_  2048
#define BT_   (B_*T_)
#define EPS_  1.1920928955078125e-07f
#define LOG2E_ 1.4426950408889634f

typedef __bf16 bf16x8 __attribute__((ext_vector_type(8)));
typedef float  f32x4  __attribute__((ext_vector_type(4)));

__device__ inline unsigned short f2bf(float f) {
    unsigned int u = __float_as_uint(f);
    u += 0x7fff + ((u >> 16) & 1);   // round-to-nearest-even
    return (unsigned short)(u >> 16);
}
__device__ inline float bf2f(unsigned short u) {
    return __uint_as_float(((unsigned int)u) << 16);
}
// exp2: hardware v_exp_f32 (avoid __exp2f: glibc macro clash on this toolchain)
__device__ inline float fast_exp2(float x) { return __builtin_amdgcn_exp2f(x); }

#define GLOAD_LDS16(gp, lp)                                                        \
    __builtin_amdgcn_global_load_lds(                                              \
        (const __attribute__((address_space(1))) void*)(gp),                       \
        (__attribute__((address_space(3))) void*)(lp), 16, 0, 0)

// ---------------------------------------------------------------- batched f32 -> bf16 (one launch)
struct CvtArgs {
    const float* src[6];
    unsigned short* dst[6];
    int start4[6];   // cumulative float4 offsets
};
__global__ __launch_bounds__(256) void cvt_all(CvtArgs a, int total4) {
    int i = blockIdx.x * 256 + threadIdx.x;
    if (i >= total4) return;
    int s = 0;
#pragma unroll
    for (int k = 1; k < 6; k++) s += (i >= a.start4[k]) ? 1 : 0;
    int j = i - a.start4[s];
    float4 v = ((const float4*)a.src[s])[j];
    ushort4 o;
    o.x = f2bf(v.x); o.y = f2bf(v.y); o.z = f2bf(v.z); o.w = f2bf(v.w);
    ((ushort4*)a.dst[s])[j] = o;
}

// ---------------------------------------------------------------- GEMM C = A * W^T  (m97 recipe)
__device__ inline void store_out(float* p, float v) { *p = v; }
__device__ inline void store_out(unsigned short* p, float v) { *p = f2bf(v); }

template <typename OT>
__global__ __launch_bounds__(256) void gemm_bt(const unsigned short* __restrict__ A,
                                               const unsigned short* __restrict__ W,
                                               OT* __restrict__ C,
                                               int M, int N, int K) {
    __shared__ unsigned short As[128][32];
    __shared__ unsigned short Ws[128][32];
    int tid  = threadIdx.x;
    int lane = tid & 63, wave = tid >> 6;
    int quad = lane >> 4, l16 = lane & 15;
    int wm = (wave >> 1) * 64, wn = (wave & 1) * 64;
    long m0 = (long)blockIdx.y * 128, n0 = (long)blockIdx.x * 128;

    int sr = wave * 32 + (lane >> 2);
    int scl = (lane & 3) * 8;
    const unsigned short* Ag0 = A + (m0 + sr) * K + scl;
    const unsigned short* Ag1 = A + (m0 + sr + 16) * K + scl;
    const unsigned short* Wg0 = W + (n0 + sr) * K + scl;
    const unsigned short* Wg1 = W + (n0 + sr + 16) * K + scl;
    unsigned short* Al0 = &As[wave * 32][0];
    unsigned short* Al1 = &As[wave * 32 + 16][0];
    unsigned short* Wl0 = &Ws[wave * 32][0];
    unsigned short* Wl1 = &Ws[wave * 32 + 16][0];

    f32x4 acc[4][4];
#pragma unroll
    for (int i = 0; i < 4; i++)
#pragma unroll
        for (int j = 0; j < 4; j++) acc[i][j] = (f32x4){0.f, 0.f, 0.f, 0.f};

    for (int k0 = 0; k0 < K; k0 += 32) {
        __syncthreads();
        GLOAD_LDS16(Ag0 + k0, Al0);
        GLOAD_LDS16(Ag1 + k0, Al1);
        GLOAD_LDS16(Wg0 + k0, Wl0);
        GLOAD_LDS16(Wg1 + k0, Wl1);
        __syncthreads();
        bf16x8 af[4], wf[4];
#pragma unroll
        for (int i = 0; i < 4; i++) af[i] = *(const bf16x8*)&As[wm + i * 16 + l16][quad * 8];
#pragma unroll
        for (int j = 0; j < 4; j++) wf[j] = *(const bf16x8*)&Ws[wn + j * 16 + l16][quad * 8];
#pragma unroll
        for (int i = 0; i < 4; i++)
#pragma unroll
            for (int j = 0; j < 4; j++)
                acc[i][j] = __builtin_amdgcn_mfma_f32_16x16x32_bf16(af[i], wf[j], acc[i][j], 0, 0, 0);
    }
#pragma unroll
    for (int i = 0; i < 4; i++)
#pragma unroll
        for (int j = 0; j < 4; j++)
#pragma unroll
            for (int r = 0; r < 4; r++) {
                long row = m0 + wm + i * 16 + quad * 4 + r;
                long col = n0 + wn + j * 16 + l16;
                store_out(&C[row * N + col], acc[i][j][r]);
            }
}

// GEMM with split destination: block-columns < N1 -> C1 (ld N1), else C2 (ld N-N1). Both bf16.
__global__ __launch_bounds__(256) void gemm_split(const unsigned short* __restrict__ A,
                                                  const unsigned short* __restrict__ W,
                                                  unsigned short* __restrict__ C1, int N1,
                                                  unsigned short* __restrict__ C2,
                                                  int M, int N, int K) {
    __shared__ unsigned short As[128][32];
    __shared__ unsigned short Ws[128][32];
    int tid  = threadIdx.x;
    int lane = tid & 63, wave = tid >> 6;
    int quad = lane >> 4, l16 = lane & 15;
    int wm = (wave >> 1) * 64, wn = (wave & 1) * 64;
    long m0 = (long)blockIdx.y * 128, n0 = (long)blockIdx.x * 128;

    int sr = wave * 32 + (lane >> 2);
    int scl = (lane & 3) * 8;
    const unsigned short* Ag0 = A + (m0 + sr) * K + scl;
    const unsigned short* Ag1 = A + (m0 + sr + 16) * K + scl;
    const unsigned short* Wg0 = W + (n0 + sr) * K + scl;
    const unsigned short* Wg1 = W + (n0 + sr + 16) * K + scl;
    unsigned short* Al0 = &As[wave * 32][0];
    unsigned short* Al1 = &As[wave * 32 + 16][0];
    unsigned short* Wl0 = &Ws[wave * 32][0];
    unsigned short* Wl1 = &Ws[wave * 32 + 16][0];

    f32x4 acc[4][4];
#pragma unroll
    for (int i = 0; i < 4; i++)
#pragma unroll
        for (int j = 0; j < 4; j++) acc[i][j] = (f32x4){0.f, 0.f, 0.f, 0.f};

    for (int k0 = 0; k0 < K; k0 += 32) {
        __syncthreads();
        GLOAD_LDS16(Ag0 + k0, Al0);
        GLOAD_LDS16(Ag1 + k0, Al1);
        GLOAD_LDS16(Wg0 + k0, Wl0);
        GLOAD_LDS16(Wg1 + k0, Wl1);
        __syncthreads();
        bf16x8 af[4], wf[4];
#pragma unroll
        for (int i = 0; i < 4; i++) af[i] = *(const bf16x8*)&As[wm + i * 16 + l16][quad * 8];
#pragma unroll
        for (int j = 0; j < 4; j++) wf[j] = *(const bf16x8*)&Ws[wn + j * 16 + l16][quad * 8];
#pragma unroll
        for (int i = 0; i < 4; i++)
#pragma unroll
            for (int j = 0; j < 4; j++)
                acc[i][j] = __builtin_amdgcn_mfma_f32_16x16x32_bf16(af[i], wf[j], acc[i][j], 0, 0, 0);
    }
    unsigned short* Cb;
    long ldc, nb;
    if (n0 < N1) { Cb = C1; ldc = N1;     nb = n0; }
    else         { Cb = C2; ldc = N - N1; nb = n0 - N1; }
#pragma unroll
    for (int i = 0; i < 4; i++)
#pragma unroll
        for (int j = 0; j < 4; j++)
#pragma unroll
            for (int r = 0; r < 4; r++) {
                long row = m0 + wm + i * 16 + quad * 4 + r;
                long col = nb + wn + j * 16 + l16;
                Cb[row * ldc + col] = f2bf(acc[i][j][r]);
            }
}

// ---------------------------------------------------------------- RMS-norm + RoPE (+gain), bf16 in
// Q path folds gain * 1/sqrt(128) * log2(e)  (attention runs in exp2 domain)
template <int NHEADS, bool GAIN>
__global__ __launch_bounds__(256) void qk_prep(const unsigned short* __restrict__ lin,
                                               const float* __restrict__ gain,
                                               unsigned short* __restrict__ out,
                                               int incols) {
    int r    = blockIdx.x * 4 + (threadIdx.x >> 6);
    int lane = threadIdx.x & 63;
    int bt = r / NHEADS, h = r % NHEADS;
    const unsigned short* ip = lin + (long)bt * incols + h * 128;
    float x1 = bf2f(ip[lane]), x2 = bf2f(ip[lane + 64]);
    float ss = x1 * x1 + x2 * x2;
#pragma unroll
    for (int off = 32; off; off >>= 1) ss += __shfl_xor(ss, off);
    float inv = rsqrtf(ss * (1.0f / 128.0f) + EPS_);
    x1 *= inv; x2 *= inv;
    int b = bt / T_, t = bt % T_;
    float freq = expf(-(float)lane * 0.14391156463f);   // ln(10000)/64
    float f = (float)t * freq;
    float s, c;
    sincosf(f, &s, &c);
    float g = GAIN ? gain[h] * 0.08838834764831845f * LOG2E_ : 1.0f;
    float o1 = (x1 * c + x2 * s) * g;
    float o2 = (x2 * c - x1 * s) * g;
    unsigned short* op = out + ((long)(b * NHEADS + h) * T_ + t) * 128;
    op[lane]      = f2bf(o1);
    op[lane + 64] = f2bf(o2);
}

// ---------------------------------------------------------------- V transpose: kv_lin cols 512..1023 (bf16) -> (B,NKV,128,T) bf16
__global__ __launch_bounds__(256) void v_transpose(const unsigned short* __restrict__ vlin,
                                                   unsigned short* __restrict__ vt) {
    __shared__ unsigned short tile[32][33];
    int bkv = blockIdx.z, b = bkv >> 2, kv = bkv & 3;
    int t0 = blockIdx.x * 32, d0 = blockIdx.y * 32;
    int tx = threadIdx.x & 31, ty = threadIdx.x >> 5;
#pragma unroll
    for (int rr = 0; rr < 32; rr += 8) {
        int t = t0 + ty + rr;
        tile[ty + rr][tx] = vlin[((long)(b * T_ + t)) * 1024 + 512 + kv * 128 + d0 + tx];
    }
    __syncthreads();
#pragma unroll
    for (int rr = 0; rr < 32; rr += 8) {
        int d = d0 + ty + rr;
        vt[((long)((b * NKV_ + kv) * 128 + d)) * T_ + t0 + tx] = tile[tx][ty + rr];
    }
}

// ---------------------------------------------------------------- flash attention
// Block = (b,kv,h',qb,c). XCD swizzle: blockIdx%8 = (b*4+kv) so the 160 blocks sharing one
// K/V pair (2 MB) live on one XCD's L2. 4 waves x 32 q rows; kv chunk = up to 8x64 tiles.
// LDS: Vs2 16KB persistent + KsPt 18KB (K tile during QK, P^T bounce during softmax/PV).
// __launch_bounds__(256,3): 3 waves/SIMD -> ~170-reg budget, NO SPILL.
// (256,4) spilled Ot to scratch: VGPR 64, 575 MB scratch traffic, 2x slower (R5 post-mortem).
__global__ __launch_bounds__(256, 3) void attn_kernel(const unsigned short* __restrict__ Q,
                                                      const unsigned short* __restrict__ Km,
                                                      const unsigned short* __restrict__ Vt,
                                                      unsigned short* __restrict__ po,
                                                      float* __restrict__ pm,
                                                      float* __restrict__ pl) {
    __shared__ alignas(16) unsigned short Vs2[2][128][32];   // [kv-chunk][d][kv in chunk]
    __shared__ alignas(16) unsigned short KsPt[4 * 32 * 72]; // K: [4][64][32] / P^T: [4][32][72]

    int tid = threadIdx.x, lane = tid & 63, wave = tid >> 6;
    int quad = lane >> 4, l16 = lane & 15;

    int g8 = blockIdx.x & 7;          // XCD slot = (b*4+kv)
    int j5 = blockIdx.x >> 3;         // 0..159 within the kv-group
    int hh = j5 / 40;                 // head within kv group
    int rem = j5 % 40;
    int b = g8 >> 2, kvh = g8 & 3, h = kvh * 4 + hh, bh = b * 16 + h;
    int g, loc;
    if      (rem <  4) { g = 0; loc = rem;      }
    else if (rem < 12) { g = 1; loc = rem - 4;  }
    else if (rem < 24) { g = 2; loc = rem - 12; }
    else               { g = 3; loc = rem - 24; }
    int qb = g * 4 + loc / (g + 1);
    int c  = loc % (g + 1);
    int Q0 = qb * 128 + wave * 32;

    int kt0 = c * 8;
    int nt  = min(8, 2 * qb + 2 - kt0);

    const unsigned short* qp = Q + ((long)(b * NH_ + h) * T_ + Q0) * 128;
    const char* kb = (const char*)(Km + (long)(b * NKV_ + kvh) * T_ * 128);
    const char* vb = (const char*)(Vt + (long)(b * NKV_ + kvh) * 128 * (long)T_);
    char* ksB = (char*)&KsPt[0];
    char* vsB = (char*)&Vs2[0][0][0];
    unsigned short* PtW = &KsPt[wave * 2304];   // [32][72] per wave

    bf16x8 Qf[2][4];
#pragma unroll
    for (int u = 0; u < 2; u++)
#pragma unroll
        for (int s = 0; s < 4; s++)
            Qf[u][s] = *(const bf16x8*)&qp[(u * 16 + l16) * 128 + s * 32 + quad * 8];

    f32x4 Ot[8][2];
#pragma unroll
    for (int n = 0; n < 8; n++)
#pragma unroll
        for (int u = 0; u < 2; u++) Ot[n][u] = (f32x4){0.f, 0.f, 0.f, 0.f};
    float mr[2] = {-3.0e38f, -3.0e38f}, ls[2] = {0.f, 0.f};

    for (int kt = kt0; kt < kt0 + nt; kt++) {
        int tb = kt * 64;
        __syncthreads();   // (1) prior tile's P/V reads done before restaging
        {   // stage K: wave = d-chunk s
            const char* kg = kb + (long)tb * 256 + wave * 64 + (lane >> 2) * 256 + (lane & 3) * 16;
            char* kl = ksB + wave * 4096 + lane * 16;
#pragma unroll
            for (int r = 0; r < 4; r++)
                GLOAD_LDS16(kg + r * 4096, kl + r * 1024);
        }
        {   // stage V
            int h2 = wave >> 1;
            int D0 = (wave & 1) * 64;
#pragma unroll
            for (int r = 0; r < 4; r++) {
                int D = D0 + r * 16;
                const char* vgr = vb + (long)(D + (lane >> 2)) * 4096 + (long)tb * 2 + h2 * 64 + (lane & 3) * 16;
                char* vl = vsB + h2 * 8192 + D * 64 + lane * 16;
                GLOAD_LDS16(vgr, vl);
            }
        }
        __syncthreads();   // (2) staged data visible

        f32x4 sc[4][2];
#pragma unroll
        for (int j = 0; j < 4; j++)
#pragma unroll
            for (int u = 0; u < 2; u++) sc[j][u] = (f32x4){0.f, 0.f, 0.f, 0.f};
#pragma unroll
        for (int j = 0; j < 4; j++)
#pragma unroll
            for (int s = 0; s < 4; s++) {
                bf16x8 kf = *(const bf16x8*)&KsPt[s * 2048 + (j * 16 + l16) * 32 + quad * 8];
                sc[j][0] = __builtin_amdgcn_mfma_f32_16x16x32_bf16(kf, Qf[0][s], sc[j][0], 0, 0, 0);
                sc[j][1] = __builtin_amdgcn_mfma_f32_16x16x32_bf16(kf, Qf[1][s], sc[j][1], 0, 0, 0);
            }
        __syncthreads();   // (3) all QK reads of K done; KsPt becomes P^T bounce

#pragma unroll
        for (int u = 0; u < 2; u++) {
            if (tb + 63 > Q0 + u * 16) {            // boundary tile (wave-uniform branch)
                int qg = Q0 + u * 16 + l16;
#pragma unroll
                for (int j = 0; j < 4; j++)
#pragma unroll
                    for (int r = 0; r < 4; r++) {
                        int kvg = tb + j * 16 + quad * 4 + r;
                        if (kvg > qg) sc[j][u][r] = -3.0e38f;
                    }
            }
            float mx = -3.0e38f;
#pragma unroll
            for (int j = 0; j < 4; j++)
#pragma unroll
                for (int r = 0; r < 4; r++) mx = fmaxf(mx, sc[j][u][r]);
            mx = fmaxf(mx, __shfl_xor(mx, 16));
            mx = fmaxf(mx, __shfl_xor(mx, 32));
            float mnew  = fmaxf(mr[u], mx);
            float alpha = fast_exp2(mr[u] - mnew);
            float ps = 0.f;
#pragma unroll
            for (int j = 0; j < 4; j++) {
                ushort4 pk;
                float p0 = fast_exp2(sc[j][u][0] - mnew);
                float p1 = fast_exp2(sc[j][u][1] - mnew);
                float p2 = fast_exp2(sc[j][u][2] - mnew);
                float p3 = fast_exp2(sc[j][u][3] - mnew);
                ps += (p0 + p1) + (p2 + p3);
                pk.x = f2bf(p0); pk.y = f2bf(p1); pk.z = f2bf(p2); pk.w = f2bf(p3);
                *(ushort4*)&PtW[(u * 16 + l16) * 72 + j * 16 + quad * 4] = pk;
            }
            ps += __shfl_xor(ps, 16);
            ps += __shfl_xor(ps, 32);
            ls[u] = ls[u] * alpha + ps;
            mr[u] = mnew;
#pragma unroll
            for (int n = 0; n < 8; n++) Ot[n][u] *= alpha;
        }
        __threadfence_block();   // wave-private P^T writes -> reads

#pragma unroll
        for (int h2 = 0; h2 < 2; h2++) {
            bf16x8 pf0 = *(const bf16x8*)&PtW[(0 * 16 + l16) * 72 + h2 * 32 + quad * 8];
            bf16x8 pf1 = *(const bf16x8*)&PtW[(1 * 16 + l16) * 72 + h2 * 32 + quad * 8];
#pragma unroll
            for (int n = 0; n < 8; n++) {
                bf16x8 vf = *(const bf16x8*)&Vs2[h2][n * 16 + l16][quad * 8];
                Ot[n][0] = __builtin_amdgcn_mfma_f32_16x16x32_bf16(vf, pf0, Ot[n][0], 0, 0, 0);
                Ot[n][1] = __builtin_amdgcn_mfma_f32_16x16x32_bf16(vf, pf1, Ot[n][1], 0, 0, 0);
            }
        }
    }

    // epilogue: transpose O^T -> O rows via own wave's PtW slice, 16B stores
    int i2 = qb * 4 + wave;
    long slot = (long)bh * 160 + 8 * g * (g + 1) + (long)(i2 & 15) * (g + 1) + c;
#pragma unroll
    for (int half = 0; half < 2; half++) {
        __threadfence_block();
#pragma unroll
        for (int n2 = 0; n2 < 4; n2++) {
            int n = half * 4 + n2;
#pragma unroll
            for (int u = 0; u < 2; u++) {
                ushort4 pk;
                pk.x = f2bf(Ot[n][u][0]); pk.y = f2bf(Ot[n][u][1]);
                pk.z = f2bf(Ot[n][u][2]); pk.w = f2bf(Ot[n][u][3]);
                *(ushort4*)&PtW[(u * 16 + l16) * 72 + n2 * 16 + quad * 4] = pk;
            }
        }
        __threadfence_block();
#pragma unroll
        for (int rr = 0; rr < 4; rr++) {
            int qrow = rr * 8 + (lane >> 3);
            int colseg = (lane & 7) * 8;
            uint4 val = *(const uint4*)&PtW[qrow * 72 + colseg];
            *(uint4*)&po[slot * 4096 + qrow * 128 + half * 64 + colseg] = val;
        }
    }
    if (lane < 16) {
        pm[slot * 32 + lane]      = mr[0];
        pm[slot * 32 + 16 + lane] = mr[1];
        pl[slot * 32 + lane]      = ls[0];
        pl[slot * 32 + 16 + lane] = ls[1];
    }
}

// ---------------------------------------------------------------- split-K combine -> Y (B,T,DIM) bf16
__global__ __launch_bounds__(256) void attn_combine(const unsigned short* __restrict__ po,
                                                    const float* __restrict__ pm,
                                                    const float* __restrict__ pl,
                                                    unsigned short* __restrict__ Y) {
    int bh = blockIdx.x >> 6, i2 = blockIdx.x & 63;
    int g = i2 >> 4, nc = g + 1;
    long slot0 = (long)bh * 160 + 8 * g * (g + 1) + (long)(i2 & 15) * nc;
    int col = threadIdx.x & 127;
    int r0  = threadIdx.x >> 7;
    int b = bh >> 4, h = bh & 15;
    for (int r = r0; r < 32; r += 2) {
        float M = -3.0e38f;
        for (int c = 0; c < nc; c++) M = fmaxf(M, pm[(slot0 + c) * 32 + r]);
        float L = 0.f, acc = 0.f;
        for (int c = 0; c < nc; c++) {
            float w = fast_exp2(pm[(slot0 + c) * 32 + r] - M);
            L   += pl[(slot0 + c) * 32 + r] * w;
            acc += w * bf2f(po[(slot0 + c) * 4096 + r * 128 + col]);
        }
        Y[((long)b * T_ + i2 * 32 + r) * DIM_ + h * 128 + col] = f2bf(acc / L);
    }
}

// ---------------------------------------------------------------- launch
extern "C" void kernel_launch(void* const* d_in, const int* in_sizes, int n_in,
                              void* d_out, int out_size, void* d_ws, size_t ws_size,
                              hipStream_t stream) {
    const float* x     = (const float*)d_in[0];
    const float* Wq    = (const float*)d_in[1];
    const float* Wdown = (const float*)d_in[2];
    const float* Wkup  = (const float*)d_in[3];
    const float* Wvup  = (const float*)d_in[4];
    const float* Wproj = (const float*)d_in[5];
    const float* qgain = (const float*)d_in[6];

    char* ws = (char*)d_ws;
    size_t off = 0;
    auto alloc = [&](size_t bytes) -> void* {
        void* p = ws + off;
        off += (bytes + 255) & ~(size_t)255;
        return p;
    };
    // region 1: live through the whole pipeline
    unsigned short* Wp_bf  = (unsigned short*)alloc((size_t)DIM_ * DIM_ * 2);
    unsigned short* q_bf   = (unsigned short*)alloc((size_t)BT_ * DIM_ * 2);
    unsigned short* k_bf   = (unsigned short*)alloc((size_t)B_ * NKV_ * T_ * 128 * 2);
    unsigned short* vT_bf  = (unsigned short*)alloc((size_t)B_ * NKV_ * T_ * 128 * 2);
    unsigned short* y_bf   = (unsigned short*)alloc((size_t)BT_ * DIM_ * 2);
    // region 2: dead before attn -> overlaid by split-K partials
    char* region2 = ws + off;
    unsigned short* x_bf   = (unsigned short*)alloc((size_t)BT_ * DIM_ * 2);
    unsigned short* Wqd_bf = (unsigned short*)alloc((size_t)2560 * DIM_ * 2);   // [Wq;Wdown]
    unsigned short* Wkv_bf = (unsigned short*)alloc((size_t)1024 * RANK_ * 2);  // [Wkup;Wvup]
    unsigned short* q_lin  = (unsigned short*)alloc((size_t)BT_ * DIM_ * 2);
    unsigned short* lat_bf = (unsigned short*)alloc((size_t)BT_ * RANK_ * 2);
    unsigned short* kv_lin = (unsigned short*)alloc((size_t)BT_ * 1024 * 2);

    unsigned short* po = (unsigned short*)region2;                     // 5120*4096*2 = 41.9 MB
    float* pm = (float*)(region2 + (size_t)5120 * 4096 * 2);           // 0.65 MB
    float* pl = pm + 5120 * 32;                                        // 0.65 MB

    // one batched cvt launch for all six f32->bf16 casts
    CvtArgs ca;
    ca.src[0] = x;     ca.dst[0] = x_bf;
    ca.src[1] = Wq;    ca.dst[1] = Wqd_bf;
    ca.src[2] = Wdown; ca.dst[2] = Wqd_bf + (size_t)DIM_ * DIM_;
    ca.src[3] = Wkup;  ca.dst[3] = Wkv_bf;
    ca.src[4] = Wvup;  ca.dst[4] = Wkv_bf + (size_t)512 * RANK_;
    ca.src[5] = Wproj; ca.dst[5] = Wp_bf;
    int n4[6] = {BT_ * DIM_ / 4, DIM_ * DIM_ / 4, RANK_ * DIM_ / 4,
                 512 * RANK_ / 4, 512 * RANK_ / 4, DIM_ * DIM_ / 4};
    int acc4 = 0;
    for (int i = 0; i < 6; i++) { ca.start4[i] = acc4; acc4 += n4[i]; }
    cvt_all<<<(acc4 + 255) / 256, 256, 0, stream>>>(ca, acc4);

    // fused [q_lin | lat] = x @ [Wq;Wdown]^T
    gemm_split<<<dim3(2560 / 128, BT_ / 128), 256, 0, stream>>>(x_bf, Wqd_bf, q_lin, DIM_, lat_bf, BT_, 2560, DIM_);
    // kv_lin = lat @ [Wkup;Wvup]^T
    gemm_bt<unsigned short><<<dim3(1024 / 128, BT_ / 128), 256, 0, stream>>>(lat_bf, Wkv_bf, kv_lin, BT_, 1024, RANK_);

    qk_prep<NH_, true><<<BT_ * NH_ / 4, 256, 0, stream>>>(q_lin, qgain, q_bf, DIM_);
    qk_prep<NKV_, false><<<BT_ * NKV_ / 4, 256, 0, stream>>>(kv_lin, qgain, k_bf, 1024);
    v_transpose<<<dim3(T_ / 32, 128 / 32, B_ * NKV_), 256, 0, stream>>>(kv_lin, vT_bf);

    attn_kernel<<<dim3(32 * 40), 256, 0, stream>>>(q_bf, k_bf, vT_bf, po, pm, pl);
    attn_combine<<<dim3(32 * 64), 256, 0, stream>>>(po, pm, pl, y_bf);

    gemm_bt<float><<<dim3(DIM_ / 128, BT_ / 128), 256, 0, stream>>>(y_bf, Wp_bf, (float*)d_out, BT_, DIM_, DIM_);
}

// Round 7
// 398.933 us; speedup vs baseline: 1.2964x; 1.0187x over previous
//
#include <hip/hip_runtime.h>
#include <stdint.h>

#define B_    2
#define T_    2048
#define NH_   16
#define NKV_  4
#define HD_   128
#define RANK_ 512
#define DIM_  2048
#define BT_   (B_*T_)
#define EPS_  1.1920928955078125e-07f
#define LOG2E_ 1.4426950408889634f
#define CT_   6              // kv-tiles per attn chunk (balanced split-K)
#define SLOTS_PER_BH_ 204    // 4 * sum_qb ceil((qb+1)/3) = 4*51

typedef __bf16 bf16x8 __attribute__((ext_vector_type(8)));
typedef float  f32x4  __attribute__((ext_vector_type(4)));

__device__ inline unsigned short f2bf(float f) {
    unsigned int u = __float_as_uint(f);
    u += 0x7fff + ((u >> 16) & 1);   // round-to-nearest-even
    return (unsigned short)(u >> 16);
}
__device__ inline float bf2f(unsigned short u) {
    return __uint_as_float(((unsigned int)u) << 16);
}
// exp2: hardware v_exp_f32 (avoid __exp2f: glibc macro clash on this toolchain)
__device__ inline float fast_exp2(float x) { return __builtin_amdgcn_exp2f(x); }

#define GLOAD_LDS16(gp, lp)                                                        \
    __builtin_amdgcn_global_load_lds(                                              \
        (const __attribute__((address_space(1))) void*)(gp),                       \
        (__attribute__((address_space(3))) void*)(lp), 16, 0, 0)

// ---------------------------------------------------------------- batched f32 -> bf16 (one launch)
struct CvtArgs {
    const float* src[6];
    unsigned short* dst[6];
    int start4[6];   // cumulative float4 offsets
};
__global__ __launch_bounds__(256) void cvt_all(CvtArgs a, int total4) {
    int i = blockIdx.x * 256 + threadIdx.x;
    if (i >= total4) return;
    int s = 0;
#pragma unroll
    for (int k = 1; k < 6; k++) s += (i >= a.start4[k]) ? 1 : 0;
    int j = i - a.start4[s];
    float4 v = ((const float4*)a.src[s])[j];
    ushort4 o;
    o.x = f2bf(v.x); o.y = f2bf(v.y); o.z = f2bf(v.z); o.w = f2bf(v.w);
    ((ushort4*)a.dst[s])[j] = o;
}

// ---------------------------------------------------------------- GEMM C = A * W^T
// m97 recipe + BK=64: two 32-col sub-tiles staged per barrier pair (halves barrier drains).
__device__ inline void store_out(float* p, float v) { *p = v; }
__device__ inline void store_out(unsigned short* p, float v) { *p = f2bf(v); }

template <typename OT>
__global__ __launch_bounds__(256) void gemm_bt(const unsigned short* __restrict__ A,
                                               const unsigned short* __restrict__ W,
                                               OT* __restrict__ C,
                                               int M, int N, int K) {
    __shared__ unsigned short As[2][128][32];
    __shared__ unsigned short Ws[2][128][32];
    int tid  = threadIdx.x;
    int lane = tid & 63, wave = tid >> 6;
    int quad = lane >> 4, l16 = lane & 15;
    int wm = (wave >> 1) * 64, wn = (wave & 1) * 64;
    long m0 = (long)blockIdx.y * 128, n0 = (long)blockIdx.x * 128;

    int sr = wave * 32 + (lane >> 2);
    int scl = (lane & 3) * 8;
    const unsigned short* Ag0 = A + (m0 + sr) * K + scl;
    const unsigned short* Ag1 = A + (m0 + sr + 16) * K + scl;
    const unsigned short* Wg0 = W + (n0 + sr) * K + scl;
    const unsigned short* Wg1 = W + (n0 + sr + 16) * K + scl;
    unsigned short* Al0 = &As[0][wave * 32][0];
    unsigned short* Al1 = &As[0][wave * 32 + 16][0];
    unsigned short* Wl0 = &Ws[0][wave * 32][0];
    unsigned short* Wl1 = &Ws[0][wave * 32 + 16][0];

    f32x4 acc[4][4];
#pragma unroll
    for (int i = 0; i < 4; i++)
#pragma unroll
        for (int j = 0; j < 4; j++) acc[i][j] = (f32x4){0.f, 0.f, 0.f, 0.f};

    for (int k0 = 0; k0 < K; k0 += 64) {
        __syncthreads();
        GLOAD_LDS16(Ag0 + k0, Al0);
        GLOAD_LDS16(Ag1 + k0, Al1);
        GLOAD_LDS16(Wg0 + k0, Wl0);
        GLOAD_LDS16(Wg1 + k0, Wl1);
        GLOAD_LDS16(Ag0 + k0 + 32, Al0 + 4096);
        GLOAD_LDS16(Ag1 + k0 + 32, Al1 + 4096);
        GLOAD_LDS16(Wg0 + k0 + 32, Wl0 + 4096);
        GLOAD_LDS16(Wg1 + k0 + 32, Wl1 + 4096);
        __syncthreads();
#pragma unroll
        for (int p = 0; p < 2; p++) {
            bf16x8 af[4], wf[4];
#pragma unroll
            for (int i = 0; i < 4; i++) af[i] = *(const bf16x8*)&As[p][wm + i * 16 + l16][quad * 8];
#pragma unroll
            for (int j = 0; j < 4; j++) wf[j] = *(const bf16x8*)&Ws[p][wn + j * 16 + l16][quad * 8];
#pragma unroll
            for (int i = 0; i < 4; i++)
#pragma unroll
                for (int j = 0; j < 4; j++)
                    acc[i][j] = __builtin_amdgcn_mfma_f32_16x16x32_bf16(af[i], wf[j], acc[i][j], 0, 0, 0);
        }
    }
#pragma unroll
    for (int i = 0; i < 4; i++)
#pragma unroll
        for (int j = 0; j < 4; j++)
#pragma unroll
            for (int r = 0; r < 4; r++) {
                long row = m0 + wm + i * 16 + quad * 4 + r;
                long col = n0 + wn + j * 16 + l16;
                store_out(&C[row * N + col], acc[i][j][r]);
            }
}

// GEMM with split destination: block-columns < N1 -> C1 (ld N1), else C2 (ld N-N1). Both bf16.
__global__ __launch_bounds__(256) void gemm_split(const unsigned short* __restrict__ A,
                                                  const unsigned short* __restrict__ W,
                                                  unsigned short* __restrict__ C1, int N1,
                                                  unsigned short* __restrict__ C2,
                                                  int M, int N, int K) {
    __shared__ unsigned short As[2][128][32];
    __shared__ unsigned short Ws[2][128][32];
    int tid  = threadIdx.x;
    int lane = tid & 63, wave = tid >> 6;
    int quad = lane >> 4, l16 = lane & 15;
    int wm = (wave >> 1) * 64, wn = (wave & 1) * 64;
    long m0 = (long)blockIdx.y * 128, n0 = (long)blockIdx.x * 128;

    int sr = wave * 32 + (lane >> 2);
    int scl = (lane & 3) * 8;
    const unsigned short* Ag0 = A + (m0 + sr) * K + scl;
    const unsigned short* Ag1 = A + (m0 + sr + 16) * K + scl;
    const unsigned short* Wg0 = W + (n0 + sr) * K + scl;
    const unsigned short* Wg1 = W + (n0 + sr + 16) * K + scl;
    unsigned short* Al0 = &As[0][wave * 32][0];
    unsigned short* Al1 = &As[0][wave * 32 + 16][0];
    unsigned short* Wl0 = &Ws[0][wave * 32][0];
    unsigned short* Wl1 = &Ws[0][wave * 32 + 16][0];

    f32x4 acc[4][4];
#pragma unroll
    for (int i = 0; i < 4; i++)
#pragma unroll
        for (int j = 0; j < 4; j++) acc[i][j] = (f32x4){0.f, 0.f, 0.f, 0.f};

    for (int k0 = 0; k0 < K; k0 += 64) {
        __syncthreads();
        GLOAD_LDS16(Ag0 + k0, Al0);
        GLOAD_LDS16(Ag1 + k0, Al1);
        GLOAD_LDS16(Wg0 + k0, Wl0);
        GLOAD_LDS16(Wg1 + k0, Wl1);
        GLOAD_LDS16(Ag0 + k0 + 32, Al0 + 4096);
        GLOAD_LDS16(Ag1 + k0 + 32, Al1 + 4096);
        GLOAD_LDS16(Wg0 + k0 + 32, Wl0 + 4096);
        GLOAD_LDS16(Wg1 + k0 + 32, Wl1 + 4096);
        __syncthreads();
#pragma unroll
        for (int p = 0; p < 2; p++) {
            bf16x8 af[4], wf[4];
#pragma unroll
            for (int i = 0; i < 4; i++) af[i] = *(const bf16x8*)&As[p][wm + i * 16 + l16][quad * 8];
#pragma unroll
            for (int j = 0; j < 4; j++) wf[j] = *(const bf16x8*)&Ws[p][wn + j * 16 + l16][quad * 8];
#pragma unroll
            for (int i = 0; i < 4; i++)
#pragma unroll
                for (int j = 0; j < 4; j++)
                    acc[i][j] = __builtin_amdgcn_mfma_f32_16x16x32_bf16(af[i], wf[j], acc[i][j], 0, 0, 0);
        }
    }
    unsigned short* Cb;
    long ldc, nb;
    if (n0 < N1) { Cb = C1; ldc = N1;     nb = n0; }
    else         { Cb = C2; ldc = N - N1; nb = n0 - N1; }
#pragma unroll
    for (int i = 0; i < 4; i++)
#pragma unroll
        for (int j = 0; j < 4; j++)
#pragma unroll
            for (int r = 0; r < 4; r++) {
                long row = m0 + wm + i * 16 + quad * 4 + r;
                long col = nb + wn + j * 16 + l16;
                Cb[row * ldc + col] = f2bf(acc[i][j][r]);
            }
}

// ---------------------------------------------------------------- fused prep: q RMS+RoPE+gain | k RMS+RoPE | V transpose
// one launch, block-uniform branch on blockIdx
__global__ __launch_bounds__(256) void prep_all(const unsigned short* __restrict__ q_lin,
                                                const unsigned short* __restrict__ kv_lin,
                                                const float* __restrict__ gain,
                                                unsigned short* __restrict__ q_bf,
                                                unsigned short* __restrict__ k_bf,
                                                unsigned short* __restrict__ vt) {
    int bid = blockIdx.x;
    if (bid < 20480) {      // q-prep (16384) + k-prep (4096)
        bool isQ = bid < 16384;
        int nheads = isQ ? NH_ : NKV_;
        int incols = isQ ? DIM_ : 1024;
        const unsigned short* lin = isQ ? q_lin : kv_lin;
        unsigned short* out = isQ ? q_bf : k_bf;
        int base = isQ ? bid : bid - 16384;
        int r    = base * 4 + (threadIdx.x >> 6);
        int lane = threadIdx.x & 63;
        int bt = r / nheads, h = r % nheads;
        const unsigned short* ip = lin + (long)bt * incols + h * 128;
        float x1 = bf2f(ip[lane]), x2 = bf2f(ip[lane + 64]);
        float ss = x1 * x1 + x2 * x2;
#pragma unroll
        for (int off = 32; off; off >>= 1) ss += __shfl_xor(ss, off);
        float inv = rsqrtf(ss * (1.0f / 128.0f) + EPS_);
        x1 *= inv; x2 *= inv;
        int b = bt / T_, t = bt % T_;
        float freq = expf(-(float)lane * 0.14391156463f);   // ln(10000)/64
        float f = (float)t * freq;
        float s, c;
        sincosf(f, &s, &c);
        float g = isQ ? gain[h] * 0.08838834764831845f * LOG2E_ : 1.0f;  // fold scale*log2e into Q
        float o1 = (x1 * c + x2 * s) * g;
        float o2 = (x2 * c - x1 * s) * g;
        unsigned short* op = out + ((long)(b * nheads + h) * T_ + t) * 128;
        op[lane]      = f2bf(o1);
        op[lane + 64] = f2bf(o2);
    } else {                // V transpose: kv_lin cols 512..1023 -> (B,NKV,128,T)
        __shared__ unsigned short tile[32][33];
        int idx = bid - 20480;          // [0,2048)
        int tt = idx & 63, dd = (idx >> 6) & 3, bkv = idx >> 8;
        int b = bkv >> 2, kv = bkv & 3;
        int t0 = tt * 32, d0 = dd * 32;
        int tx = threadIdx.x & 31, ty = threadIdx.x >> 5;
#pragma unroll
        for (int rr = 0; rr < 32; rr += 8) {
            int t = t0 + ty + rr;
            tile[ty + rr][tx] = kv_lin[((long)(b * T_ + t)) * 1024 + 512 + kv * 128 + d0 + tx];
        }
        __syncthreads();
#pragma unroll
        for (int rr = 0; rr < 32; rr += 8) {
            int d = d0 + ty + rr;
            vt[((long)((b * NKV_ + kv) * 128 + d)) * T_ + t0 + tx] = tile[tx][ty + rr];
        }
    }
}

// ---------------------------------------------------------------- flash attention
// Block = (b,kv,h',qb,c). XCD swizzle: blockIdx%8 = (b*4+kv). 4 waves x 32 q rows.
// Balanced split-K: chunk = CT_=6 kv-tiles for every qb; nc(qb)=ceil((qb+1)/3);
// 51 chunks/bh -> 1632 blocks, longest-first launch order (rem reversed).
// LDS: Vs2 16KB + KsPt 18KB overlay (K during QK / P^T bounce after) = 34KB.
// __launch_bounds__(256,3): ~170-reg budget, NO SPILL ((256,4) spilled Ot - R5).
__global__ __launch_bounds__(256, 3) void attn_kernel(const unsigned short* __restrict__ Q,
                                                      const unsigned short* __restrict__ Km,
                                                      const unsigned short* __restrict__ Vt,
                                                      unsigned short* __restrict__ po,
                                                      float* __restrict__ pm,
                                                      float* __restrict__ pl) {
    __shared__ alignas(16) unsigned short Vs2[2][128][32];   // [kv-chunk][d][kv in chunk]
    __shared__ alignas(16) unsigned short KsPt[4 * 32 * 72]; // K: [4][64][32] / P^T: [4][32][72]

    int tid = threadIdx.x, lane = tid & 63, wave = tid >> 6;
    int quad = lane >> 4, l16 = lane & 15;

    int g8 = blockIdx.x & 7;          // XCD slot = (b*4+kv)
    int j5 = blockIdx.x >> 3;         // 0..203 (4 heads x 51 chunks)
    int hh = j5 / 51;                 // head within kv group
    int rem = 50 - (j5 % 51);         // reversed: biggest work first
    int b = g8 >> 2, kvh = g8 & 3, h = kvh * 4 + hh, bh = b * 16 + h;
    // decode rem -> (qb, c): groups a=0..4 of 3 qb each with nc=a+1; qb=15: a=5, nc=6
    int a = 0;
    while (a < 5 && 3 * (a + 1) * (a + 2) / 2 <= rem) a++;
    int off = rem - 3 * a * (a + 1) / 2;
    int nc = a + 1;
    int qb = (a == 5) ? 15 : (3 * a + off / nc);
    int c  = (a == 5) ? off : (off % nc);
    int Q0 = qb * 128 + wave * 32;

    int kt0 = c * CT_;
    int nt  = min(CT_, 2 * qb + 2 - kt0);

    const unsigned short* qp = Q + ((long)(b * NH_ + h) * T_ + Q0) * 128;
    const char* kb = (const char*)(Km + (long)(b * NKV_ + kvh) * T_ * 128);
    const char* vb = (const char*)(Vt + (long)(b * NKV_ + kvh) * 128 * (long)T_);
    char* ksB = (char*)&KsPt[0];
    char* vsB = (char*)&Vs2[0][0][0];
    unsigned short* PtW = &KsPt[wave * 2304];   // [32][72] per wave

    bf16x8 Qf[2][4];
#pragma unroll
    for (int u = 0; u < 2; u++)
#pragma unroll
        for (int s = 0; s < 4; s++)
            Qf[u][s] = *(const bf16x8*)&qp[(u * 16 + l16) * 128 + s * 32 + quad * 8];

    f32x4 Ot[8][2];
#pragma unroll
    for (int n = 0; n < 8; n++)
#pragma unroll
        for (int u = 0; u < 2; u++) Ot[n][u] = (f32x4){0.f, 0.f, 0.f, 0.f};
    float mr[2] = {-3.0e38f, -3.0e38f}, ls[2] = {0.f, 0.f};

    for (int kt = kt0; kt < kt0 + nt; kt++) {
        int tb = kt * 64;
        __syncthreads();   // (1) prior tile's P/V reads done before restaging
        {   // stage K: wave = d-chunk s
            const char* kg = kb + (long)tb * 256 + wave * 64 + (lane >> 2) * 256 + (lane & 3) * 16;
            char* kl = ksB + wave * 4096 + lane * 16;
#pragma unroll
            for (int r = 0; r < 4; r++)
                GLOAD_LDS16(kg + r * 4096, kl + r * 1024);
        }
        {   // stage V
            int h2 = wave >> 1;
            int D0 = (wave & 1) * 64;
#pragma unroll
            for (int r = 0; r < 4; r++) {
                int D = D0 + r * 16;
                const char* vgr = vb + (long)(D + (lane >> 2)) * 4096 + (long)tb * 2 + h2 * 64 + (lane & 3) * 16;
                char* vl = vsB + h2 * 8192 + D * 64 + lane * 16;
                GLOAD_LDS16(vgr, vl);
            }
        }
        __syncthreads();   // (2) staged data visible

        f32x4 sc[4][2];
#pragma unroll
        for (int j = 0; j < 4; j++)
#pragma unroll
            for (int u = 0; u < 2; u++) sc[j][u] = (f32x4){0.f, 0.f, 0.f, 0.f};
#pragma unroll
        for (int j = 0; j < 4; j++)
#pragma unroll
            for (int s = 0; s < 4; s++) {
                bf16x8 kf = *(const bf16x8*)&KsPt[s * 2048 + (j * 16 + l16) * 32 + quad * 8];
                sc[j][0] = __builtin_amdgcn_mfma_f32_16x16x32_bf16(kf, Qf[0][s], sc[j][0], 0, 0, 0);
                sc[j][1] = __builtin_amdgcn_mfma_f32_16x16x32_bf16(kf, Qf[1][s], sc[j][1], 0, 0, 0);
            }
        __syncthreads();   // (3) all QK reads of K done; KsPt becomes P^T bounce

#pragma unroll
        for (int u = 0; u < 2; u++) {
            if (tb + 63 > Q0 + u * 16) {            // boundary tile (wave-uniform branch)
                int qg = Q0 + u * 16 + l16;
#pragma unroll
                for (int j = 0; j < 4; j++)
#pragma unroll
                    for (int r = 0; r < 4; r++) {
                        int kvg = tb + j * 16 + quad * 4 + r;
                        if (kvg > qg) sc[j][u][r] = -3.0e38f;
                    }
            }
            float mx = -3.0e38f;
#pragma unroll
            for (int j = 0; j < 4; j++)
#pragma unroll
                for (int r = 0; r < 4; r++) mx = fmaxf(mx, sc[j][u][r]);
            mx = fmaxf(mx, __shfl_xor(mx, 16));
            mx = fmaxf(mx, __shfl_xor(mx, 32));
            float mnew  = fmaxf(mr[u], mx);
            float alpha = fast_exp2(mr[u] - mnew);
            float ps = 0.f;
#pragma unroll
            for (int j = 0; j < 4; j++) {
                ushort4 pk;
                float p0 = fast_exp2(sc[j][u][0] - mnew);
                float p1 = fast_exp2(sc[j][u][1] - mnew);
                float p2 = fast_exp2(sc[j][u][2] - mnew);
                float p3 = fast_exp2(sc[j][u][3] - mnew);
                ps += (p0 + p1) + (p2 + p3);
                pk.x = f2bf(p0); pk.y = f2bf(p1); pk.z = f2bf(p2); pk.w = f2bf(p3);
                *(ushort4*)&PtW[(u * 16 + l16) * 72 + j * 16 + quad * 4] = pk;
            }
            ps += __shfl_xor(ps, 16);
            ps += __shfl_xor(ps, 32);
            ls[u] = ls[u] * alpha + ps;
            mr[u] = mnew;
#pragma unroll
            for (int n = 0; n < 8; n++) Ot[n][u] *= alpha;
        }
        __threadfence_block();   // wave-private P^T writes -> reads

#pragma unroll
        for (int h2 = 0; h2 < 2; h2++) {
            bf16x8 pf0 = *(const bf16x8*)&PtW[(0 * 16 + l16) * 72 + h2 * 32 + quad * 8];
            bf16x8 pf1 = *(const bf16x8*)&PtW[(1 * 16 + l16) * 72 + h2 * 32 + quad * 8];
#pragma unroll
            for (int n = 0; n < 8; n++) {
                bf16x8 vf = *(const bf16x8*)&Vs2[h2][n * 16 + l16][quad * 8];
                Ot[n][0] = __builtin_amdgcn_mfma_f32_16x16x32_bf16(vf, pf0, Ot[n][0], 0, 0, 0);
                Ot[n][1] = __builtin_amdgcn_mfma_f32_16x16x32_bf16(vf, pf1, Ot[n][1], 0, 0, 0);
            }
        }
    }

    // epilogue: transpose O^T -> O rows via own wave's PtW slice, 16B stores
    // slot = bh*204 + 4*S(qb) + wave*nc + c;  S(qb) = rem - c
    long slot = (long)bh * SLOTS_PER_BH_ + 4 * (rem - c) + wave * nc + c;
#pragma unroll
    for (int half = 0; half < 2; half++) {
        __threadfence_block();
#pragma unroll
        for (int n2 = 0; n2 < 4; n2++) {
            int n = half * 4 + n2;
#pragma unroll
            for (int u = 0; u < 2; u++) {
                ushort4 pk;
                pk.x = f2bf(Ot[n][u][0]); pk.y = f2bf(Ot[n][u][1]);
                pk.z = f2bf(Ot[n][u][2]); pk.w = f2bf(Ot[n][u][3]);
                *(ushort4*)&PtW[(u * 16 + l16) * 72 + n2 * 16 + quad * 4] = pk;
            }
        }
        __threadfence_block();
#pragma unroll
        for (int rr = 0; rr < 4; rr++) {
            int qrow = rr * 8 + (lane >> 3);
            int colseg = (lane & 7) * 8;
            uint4 val = *(const uint4*)&PtW[qrow * 72 + colseg];
            *(uint4*)&po[slot * 4096 + qrow * 128 + half * 64 + colseg] = val;
        }
    }
    if (lane < 16) {
        pm[slot * 32 + lane]      = mr[0];
        pm[slot * 32 + 16 + lane] = mr[1];
        pl[slot * 32 + lane]      = ls[0];
        pl[slot * 32 + 16 + lane] = ls[1];
    }
}

// ---------------------------------------------------------------- split-K combine -> Y (B,T,DIM) bf16
__global__ __launch_bounds__(256) void attn_combine(const unsigned short* __restrict__ po,
                                                    const float* __restrict__ pm,
                                                    const float* __restrict__ pl,
                                                    unsigned short* __restrict__ Y) {
    int bh = blockIdx.x >> 6, i2 = blockIdx.x & 63;
    int qb = i2 >> 2, w = i2 & 3;
    int a = (qb == 15) ? 5 : qb / 3;
    int nc = a + 1;
    int S = 3 * a * (a + 1) / 2 + (qb - 3 * a) * nc;
    long slot0 = (long)bh * SLOTS_PER_BH_ + 4 * S + w * nc;
    int col = threadIdx.x & 127;
    int r0  = threadIdx.x >> 7;
    int b = bh >> 4, h = bh & 15;
    for (int r = r0; r < 32; r += 2) {
        float M = -3.0e38f;
        for (int c = 0; c < nc; c++) M = fmaxf(M, pm[(slot0 + c) * 32 + r]);
        float L = 0.f, acc = 0.f;
        for (int c = 0; c < nc; c++) {
            float wgt = fast_exp2(pm[(slot0 + c) * 32 + r] - M);
            L   += pl[(slot0 + c) * 32 + r] * wgt;
            acc += wgt * bf2f(po[(slot0 + c) * 4096 + r * 128 + col]);
        }
        Y[((long)b * T_ + i2 * 32 + r) * DIM_ + h * 128 + col] = f2bf(acc / L);
    }
}

// ---------------------------------------------------------------- launch
extern "C" void kernel_launch(void* const* d_in, const int* in_sizes, int n_in,
                              void* d_out, int out_size, void* d_ws, size_t ws_size,
                              hipStream_t stream) {
    const float* x     = (const float*)d_in[0];
    const float* Wq    = (const float*)d_in[1];
    const float* Wdown = (const float*)d_in[2];
    const float* Wkup  = (const float*)d_in[3];
    const float* Wvup  = (const float*)d_in[4];
    const float* Wproj = (const float*)d_in[5];
    const float* qgain = (const float*)d_in[6];

    char* ws = (char*)d_ws;
    size_t off = 0;
    auto alloc = [&](size_t bytes) -> void* {
        void* p = ws + off;
        off += (bytes + 255) & ~(size_t)255;
        return p;
    };
    // region 1: live through the whole pipeline
    unsigned short* Wp_bf  = (unsigned short*)alloc((size_t)DIM_ * DIM_ * 2);
    unsigned short* q_bf   = (unsigned short*)alloc((size_t)BT_ * DIM_ * 2);
    unsigned short* k_bf   = (unsigned short*)alloc((size_t)B_ * NKV_ * T_ * 128 * 2);
    unsigned short* vT_bf  = (unsigned short*)alloc((size_t)B_ * NKV_ * T_ * 128 * 2);
    unsigned short* y_bf   = (unsigned short*)alloc((size_t)BT_ * DIM_ * 2);
    // region 2: dead before attn -> overlaid by split-K partials
    char* region2 = ws + off;
    unsigned short* x_bf   = (unsigned short*)alloc((size_t)BT_ * DIM_ * 2);
    unsigned short* Wqd_bf = (unsigned short*)alloc((size_t)2560 * DIM_ * 2);   // [Wq;Wdown]
    unsigned short* Wkv_bf = (unsigned short*)alloc((size_t)1024 * RANK_ * 2);  // [Wkup;Wvup]
    unsigned short* q_lin  = (unsigned short*)alloc((size_t)BT_ * DIM_ * 2);
    unsigned short* lat_bf = (unsigned short*)alloc((size_t)BT_ * RANK_ * 2);
    unsigned short* kv_lin = (unsigned short*)alloc((size_t)BT_ * 1024 * 2);

    // partials: 32 bh * 204 slots * (32x128 bf16 + 32 m + 32 l) = 53.5 + 0.84 + 0.84 MB <= 57.7 MB region2
    const size_t NSLOT = 32 * SLOTS_PER_BH_;
    unsigned short* po = (unsigned short*)region2;
    float* pm = (float*)(region2 + NSLOT * 4096 * 2);
    float* pl = pm + NSLOT * 32;

    // one batched cvt launch for all six f32->bf16 casts
    CvtArgs ca;
    ca.src[0] = x;     ca.dst[0] = x_bf;
    ca.src[1] = Wq;    ca.dst[1] = Wqd_bf;
    ca.src[2] = Wdown; ca.dst[2] = Wqd_bf + (size_t)DIM_ * DIM_;
    ca.src[3] = Wkup;  ca.dst[3] = Wkv_bf;
    ca.src[4] = Wvup;  ca.dst[4] = Wkv_bf + (size_t)512 * RANK_;
    ca.src[5] = Wproj; ca.dst[5] = Wp_bf;
    int n4[6] = {BT_ * DIM_ / 4, DIM_ * DIM_ / 4, RANK_ * DIM_ / 4,
                 512 * RANK_ / 4, 512 * RANK_ / 4, DIM_ * DIM_ / 4};
    int acc4 = 0;
    for (int i = 0; i < 6; i++) { ca.start4[i] = acc4; acc4 += n4[i]; }
    cvt_all<<<(acc4 + 255) / 256, 256, 0, stream>>>(ca, acc4);

    // fused [q_lin | lat] = x @ [Wq;Wdown]^T
    gemm_split<<<dim3(2560 / 128, BT_ / 128), 256, 0, stream>>>(x_bf, Wqd_bf, q_lin, DIM_, lat_bf, BT_, 2560, DIM_);
    // kv_lin = lat @ [Wkup;Wvup]^T
    gemm_bt<unsigned short><<<dim3(1024 / 128, BT_ / 128), 256, 0, stream>>>(lat_bf, Wkv_bf, kv_lin, BT_, 1024, RANK_);

    // fused q-prep + k-prep + v-transpose
    prep_all<<<16384 + 4096 + 2048, 256, 0, stream>>>(q_lin, kv_lin, qgain, q_bf, k_bf, vT_bf);

    attn_kernel<<<dim3(8 * SLOTS_PER_BH_), 256, 0, stream>>>(q_bf, k_bf, vT_bf, po, pm, pl);
    attn_combine<<<dim3(32 * 64), 256, 0, stream>>>(po, pm, pl, y_bf);

    gemm_bt<float><<<dim3(DIM_ / 128, BT_ / 128), 256, 0, stream>>>(y_bf, Wp_bf, (float*)d_out, BT_, DIM_, DIM_);
}

// Round 8
// 374.339 us; speedup vs baseline: 1.3816x; 1.0657x over previous
//
#include <hip/hip_runtime.h>
#include <stdint.h>

#define B_    2
#define T_    2048
#define NH_   16
#define NKV_  4
#define HD_   128
#define RANK_ 512
#define DIM_  2048
#define BT_   (B_*T_)
#define EPS_  1.1920928955078125e-07f
#define LOG2E_ 1.4426950408889634f
#define CT_   6              // kv-tiles per attn chunk (balanced split-K)
#define CHUNKS_ 102          // sum over qb=0..31 of ceil((qb+1)/6)
#define SLOTS_PER_BH_ 408    // 4 waves * CHUNKS_

typedef __bf16 bf16x8 __attribute__((ext_vector_type(8)));
typedef float  f32x4  __attribute__((ext_vector_type(4)));

__device__ inline unsigned short f2bf(float f) {
    unsigned int u = __float_as_uint(f);
    u += 0x7fff + ((u >> 16) & 1);   // round-to-nearest-even
    return (unsigned short)(u >> 16);
}
__device__ inline float bf2f(unsigned short u) {
    return __uint_as_float(((unsigned int)u) << 16);
}
// exp2: hardware v_exp_f32 (avoid __exp2f: glibc macro clash on this toolchain)
__device__ inline float fast_exp2(float x) { return __builtin_amdgcn_exp2f(x); }

#define GLOAD_LDS16(gp, lp)                                                        \
    __builtin_amdgcn_global_load_lds(                                              \
        (const __attribute__((address_space(1))) void*)(gp),                       \
        (__attribute__((address_space(3))) void*)(lp), 16, 0, 0)

// ---------------------------------------------------------------- batched f32 -> bf16 (one launch)
struct CvtArgs {
    const float* src[6];
    unsigned short* dst[6];
    int start4[6];   // cumulative float4 offsets
};
__global__ __launch_bounds__(256) void cvt_all(CvtArgs a, int total4) {
    int i = blockIdx.x * 256 + threadIdx.x;
    if (i >= total4) return;
    int s = 0;
#pragma unroll
    for (int k = 1; k < 6; k++) s += (i >= a.start4[k]) ? 1 : 0;
    int j = i - a.start4[s];
    float4 v = ((const float4*)a.src[s])[j];
    ushort4 o;
    o.x = f2bf(v.x); o.y = f2bf(v.y); o.z = f2bf(v.z); o.w = f2bf(v.w);
    ((ushort4*)a.dst[s])[j] = o;
}

// ---------------------------------------------------------------- GEMM C = A * W^T
// m97 recipe + BK=64: two 32-col sub-tiles staged per barrier pair.
__device__ inline void store_out(float* p, float v) { *p = v; }
__device__ inline void store_out(unsigned short* p, float v) { *p = f2bf(v); }

template <typename OT>
__global__ __launch_bounds__(256) void gemm_bt(const unsigned short* __restrict__ A,
                                               const unsigned short* __restrict__ W,
                                               OT* __restrict__ C,
                                               int M, int N, int K) {
    __shared__ unsigned short As[2][128][32];
    __shared__ unsigned short Ws[2][128][32];
    int tid  = threadIdx.x;
    int lane = tid & 63, wave = tid >> 6;
    int quad = lane >> 4, l16 = lane & 15;
    int wm = (wave >> 1) * 64, wn = (wave & 1) * 64;
    long m0 = (long)blockIdx.y * 128, n0 = (long)blockIdx.x * 128;

    int sr = wave * 32 + (lane >> 2);
    int scl = (lane & 3) * 8;
    const unsigned short* Ag0 = A + (m0 + sr) * K + scl;
    const unsigned short* Ag1 = A + (m0 + sr + 16) * K + scl;
    const unsigned short* Wg0 = W + (n0 + sr) * K + scl;
    const unsigned short* Wg1 = W + (n0 + sr + 16) * K + scl;
    unsigned short* Al0 = &As[0][wave * 32][0];
    unsigned short* Al1 = &As[0][wave * 32 + 16][0];
    unsigned short* Wl0 = &Ws[0][wave * 32][0];
    unsigned short* Wl1 = &Ws[0][wave * 32 + 16][0];

    f32x4 acc[4][4];
#pragma unroll
    for (int i = 0; i < 4; i++)
#pragma unroll
        for (int j = 0; j < 4; j++) acc[i][j] = (f32x4){0.f, 0.f, 0.f, 0.f};

    for (int k0 = 0; k0 < K; k0 += 64) {
        __syncthreads();
        GLOAD_LDS16(Ag0 + k0, Al0);
        GLOAD_LDS16(Ag1 + k0, Al1);
        GLOAD_LDS16(Wg0 + k0, Wl0);
        GLOAD_LDS16(Wg1 + k0, Wl1);
        GLOAD_LDS16(Ag0 + k0 + 32, Al0 + 4096);
        GLOAD_LDS16(Ag1 + k0 + 32, Al1 + 4096);
        GLOAD_LDS16(Wg0 + k0 + 32, Wl0 + 4096);
        GLOAD_LDS16(Wg1 + k0 + 32, Wl1 + 4096);
        __syncthreads();
#pragma unroll
        for (int p = 0; p < 2; p++) {
            bf16x8 af[4], wf[4];
#pragma unroll
            for (int i = 0; i < 4; i++) af[i] = *(const bf16x8*)&As[p][wm + i * 16 + l16][quad * 8];
#pragma unroll
            for (int j = 0; j < 4; j++) wf[j] = *(const bf16x8*)&Ws[p][wn + j * 16 + l16][quad * 8];
#pragma unroll
            for (int i = 0; i < 4; i++)
#pragma unroll
                for (int j = 0; j < 4; j++)
                    acc[i][j] = __builtin_amdgcn_mfma_f32_16x16x32_bf16(af[i], wf[j], acc[i][j], 0, 0, 0);
        }
    }
#pragma unroll
    for (int i = 0; i < 4; i++)
#pragma unroll
        for (int j = 0; j < 4; j++)
#pragma unroll
            for (int r = 0; r < 4; r++) {
                long row = m0 + wm + i * 16 + quad * 4 + r;
                long col = n0 + wn + j * 16 + l16;
                store_out(&C[row * N + col], acc[i][j][r]);
            }
}

// GEMM with split destination: block-columns < N1 -> C1 (ld N1), else C2 (ld N-N1). Both bf16.
__global__ __launch_bounds__(256) void gemm_split(const unsigned short* __restrict__ A,
                                                  const unsigned short* __restrict__ W,
                                                  unsigned short* __restrict__ C1, int N1,
                                                  unsigned short* __restrict__ C2,
                                                  int M, int N, int K) {
    __shared__ unsigned short As[2][128][32];
    __shared__ unsigned short Ws[2][128][32];
    int tid  = threadIdx.x;
    int lane = tid & 63, wave = tid >> 6;
    int quad = lane >> 4, l16 = lane & 15;
    int wm = (wave >> 1) * 64, wn = (wave & 1) * 64;
    long m0 = (long)blockIdx.y * 128, n0 = (long)blockIdx.x * 128;

    int sr = wave * 32 + (lane >> 2);
    int scl = (lane & 3) * 8;
    const unsigned short* Ag0 = A + (m0 + sr) * K + scl;
    const unsigned short* Ag1 = A + (m0 + sr + 16) * K + scl;
    const unsigned short* Wg0 = W + (n0 + sr) * K + scl;
    const unsigned short* Wg1 = W + (n0 + sr + 16) * K + scl;
    unsigned short* Al0 = &As[0][wave * 32][0];
    unsigned short* Al1 = &As[0][wave * 32 + 16][0];
    unsigned short* Wl0 = &Ws[0][wave * 32][0];
    unsigned short* Wl1 = &Ws[0][wave * 32 + 16][0];

    f32x4 acc[4][4];
#pragma unroll
    for (int i = 0; i < 4; i++)
#pragma unroll
        for (int j = 0; j < 4; j++) acc[i][j] = (f32x4){0.f, 0.f, 0.f, 0.f};

    for (int k0 = 0; k0 < K; k0 += 64) {
        __syncthreads();
        GLOAD_LDS16(Ag0 + k0, Al0);
        GLOAD_LDS16(Ag1 + k0, Al1);
        GLOAD_LDS16(Wg0 + k0, Wl0);
        GLOAD_LDS16(Wg1 + k0, Wl1);
        GLOAD_LDS16(Ag0 + k0 + 32, Al0 + 4096);
        GLOAD_LDS16(Ag1 + k0 + 32, Al1 + 4096);
        GLOAD_LDS16(Wg0 + k0 + 32, Wl0 + 4096);
        GLOAD_LDS16(Wg1 + k0 + 32, Wl1 + 4096);
        __syncthreads();
#pragma unroll
        for (int p = 0; p < 2; p++) {
            bf16x8 af[4], wf[4];
#pragma unroll
            for (int i = 0; i < 4; i++) af[i] = *(const bf16x8*)&As[p][wm + i * 16 + l16][quad * 8];
#pragma unroll
            for (int j = 0; j < 4; j++) wf[j] = *(const bf16x8*)&Ws[p][wn + j * 16 + l16][quad * 8];
#pragma unroll
            for (int i = 0; i < 4; i++)
#pragma unroll
                for (int j = 0; j < 4; j++)
                    acc[i][j] = __builtin_amdgcn_mfma_f32_16x16x32_bf16(af[i], wf[j], acc[i][j], 0, 0, 0);
        }
    }
    unsigned short* Cb;
    long ldc, nb;
    if (n0 < N1) { Cb = C1; ldc = N1;     nb = n0; }
    else         { Cb = C2; ldc = N - N1; nb = n0 - N1; }
#pragma unroll
    for (int i = 0; i < 4; i++)
#pragma unroll
        for (int j = 0; j < 4; j++)
#pragma unroll
            for (int r = 0; r < 4; r++) {
                long row = m0 + wm + i * 16 + quad * 4 + r;
                long col = nb + wn + j * 16 + l16;
                Cb[row * ldc + col] = f2bf(acc[i][j][r]);
            }
}

// ---------------------------------------------------------------- fused prep: q RMS+RoPE+gain | k RMS+RoPE | V transpose
__global__ __launch_bounds__(256) void prep_all(const unsigned short* __restrict__ q_lin,
                                                const unsigned short* __restrict__ kv_lin,
                                                const float* __restrict__ gain,
                                                unsigned short* __restrict__ q_bf,
                                                unsigned short* __restrict__ k_bf,
                                                unsigned short* __restrict__ vt) {
    int bid = blockIdx.x;
    if (bid < 20480) {      // q-prep (16384) + k-prep (4096)
        bool isQ = bid < 16384;
        int nheads = isQ ? NH_ : NKV_;
        int incols = isQ ? DIM_ : 1024;
        const unsigned short* lin = isQ ? q_lin : kv_lin;
        unsigned short* out = isQ ? q_bf : k_bf;
        int base = isQ ? bid : bid - 16384;
        int r    = base * 4 + (threadIdx.x >> 6);
        int lane = threadIdx.x & 63;
        int bt = r / nheads, h = r % nheads;
        const unsigned short* ip = lin + (long)bt * incols + h * 128;
        float x1 = bf2f(ip[lane]), x2 = bf2f(ip[lane + 64]);
        float ss = x1 * x1 + x2 * x2;
#pragma unroll
        for (int off = 32; off; off >>= 1) ss += __shfl_xor(ss, off);
        float inv = rsqrtf(ss * (1.0f / 128.0f) + EPS_);
        x1 *= inv; x2 *= inv;
        int b = bt / T_, t = bt % T_;
        float freq = expf(-(float)lane * 0.14391156463f);   // ln(10000)/64
        float f = (float)t * freq;
        float s, c;
        sincosf(f, &s, &c);
        float g = isQ ? gain[h] * 0.08838834764831845f * LOG2E_ : 1.0f;  // fold scale*log2e into Q
        float o1 = (x1 * c + x2 * s) * g;
        float o2 = (x2 * c - x1 * s) * g;
        unsigned short* op = out + ((long)(b * nheads + h) * T_ + t) * 128;
        op[lane]      = f2bf(o1);
        op[lane + 64] = f2bf(o2);
    } else {                // V transpose: kv_lin cols 512..1023 -> (B,NKV,128,T)
        __shared__ unsigned short tile[32][33];
        int idx = bid - 20480;          // [0,2048)
        int tt = idx & 63, dd = (idx >> 6) & 3, bkv = idx >> 8;
        int b = bkv >> 2, kv = bkv & 3;
        int t0 = tt * 32, d0 = dd * 32;
        int tx = threadIdx.x & 31, ty = threadIdx.x >> 5;
#pragma unroll
        for (int rr = 0; rr < 32; rr += 8) {
            int t = t0 + ty + rr;
            tile[ty + rr][tx] = kv_lin[((long)(b * T_ + t)) * 1024 + 512 + kv * 128 + d0 + tx];
        }
        __syncthreads();
#pragma unroll
        for (int rr = 0; rr < 32; rr += 8) {
            int d = d0 + ty + rr;
            vt[((long)((b * NKV_ + kv) * 128 + d)) * T_ + t0 + tx] = tile[tx][ty + rr];
        }
    }
}

// ---------------------------------------------------------------- flash attention (u=1: 16 q-rows/wave)
// Block = (b,kv,h',qb,c): 64 q rows, chunk of up to CT_=6 kv-tiles. XCD swizzle blockIdx%8=(b*4+kv).
// nc(qb)=qb/6+1, 102 chunks per bh-head -> 3264 blocks, longest-first.
// LDS 32KB: Vs 16KB + KsPt 16KB (K during QK / wave-private P^T [16][72] after barrier(3)).
// __launch_bounds__(256,4): u=1 needs ~100 unified regs -> fits 128 budget (u=2 needed ~148, spilled - R5).
__global__ __launch_bounds__(256, 4) void attn_kernel(const unsigned short* __restrict__ Q,
                                                      const unsigned short* __restrict__ Km,
                                                      const unsigned short* __restrict__ Vt,
                                                      unsigned short* __restrict__ po,
                                                      float* __restrict__ pm,
                                                      float* __restrict__ pl) {
    __shared__ alignas(16) unsigned short Vs2[2][128][32];   // [kv-chunk][d][kv in chunk]
    __shared__ alignas(16) unsigned short KsPt[4 * 64 * 32]; // K [4][64][32] / P^T [4][16][72]

    int tid = threadIdx.x, lane = tid & 63, wave = tid >> 6;
    int quad = lane >> 4, l16 = lane & 15;

    int g8 = blockIdx.x & 7;          // XCD slot = (b*4+kv)
    int j5 = blockIdx.x >> 3;         // [0, 408) = 4 heads x 102 chunks
    int hh = j5 / CHUNKS_;
    int rem = (CHUNKS_ - 1) - (j5 % CHUNKS_);   // longest-first
    int b = g8 >> 2, kvh = g8 & 3, h = kvh * 4 + hh, bh = b * 16 + h;
    // decode rem -> (qb in [0,32), c): nc(qb) = qb/6+1, S = chunks before qb
    int qb = 0, S = 0;
    while (S + (qb / 6 + 1) <= rem) { S += qb / 6 + 1; ++qb; }
    int nc = qb / 6 + 1;
    int c  = rem - S;
    int Q0 = qb * 64 + wave * 16;

    int kt0 = c * CT_;
    int nt  = min(CT_, qb + 1 - kt0);

    const unsigned short* qp = Q + ((long)(b * NH_ + h) * T_ + Q0) * 128;
    const char* kb = (const char*)(Km + (long)(b * NKV_ + kvh) * T_ * 128);
    const char* vb = (const char*)(Vt + (long)(b * NKV_ + kvh) * 128 * (long)T_);
    char* ksB = (char*)&KsPt[0];
    char* vsB = (char*)&Vs2[0][0][0];
    unsigned short* PtW = &KsPt[wave * 1152];   // [16][72] per wave

    bf16x8 Qf[4];
#pragma unroll
    for (int s = 0; s < 4; s++)
        Qf[s] = *(const bf16x8*)&qp[l16 * 128 + s * 32 + quad * 8];

    f32x4 Ot[8];
#pragma unroll
    for (int n = 0; n < 8; n++) Ot[n] = (f32x4){0.f, 0.f, 0.f, 0.f};
    float mr = -3.0e38f, ls = 0.f;

    for (int kt = kt0; kt < kt0 + nt; kt++) {
        int tb = kt * 64;
        __syncthreads();   // (1) prior tile's P/V reads done before restaging
        {   // stage K: wave = d-chunk s
            const char* kg = kb + (long)tb * 256 + wave * 64 + (lane >> 2) * 256 + (lane & 3) * 16;
            char* kl = ksB + wave * 4096 + lane * 16;
#pragma unroll
            for (int r = 0; r < 4; r++)
                GLOAD_LDS16(kg + r * 4096, kl + r * 1024);
        }
        {   // stage V
            int h2 = wave >> 1;
            int D0 = (wave & 1) * 64;
#pragma unroll
            for (int r = 0; r < 4; r++) {
                int D = D0 + r * 16;
                const char* vgr = vb + (long)(D + (lane >> 2)) * 4096 + (long)tb * 2 + h2 * 64 + (lane & 3) * 16;
                char* vl = vsB + h2 * 8192 + D * 64 + lane * 16;
                GLOAD_LDS16(vgr, vl);
            }
        }
        __syncthreads();   // (2) staged data visible

        f32x4 sc[4];
#pragma unroll
        for (int j = 0; j < 4; j++) sc[j] = (f32x4){0.f, 0.f, 0.f, 0.f};
#pragma unroll
        for (int j = 0; j < 4; j++)
#pragma unroll
            for (int s = 0; s < 4; s++) {
                bf16x8 kf = *(const bf16x8*)&KsPt[s * 2048 + (j * 16 + l16) * 32 + quad * 8];
                sc[j] = __builtin_amdgcn_mfma_f32_16x16x32_bf16(kf, Qf[s], sc[j], 0, 0, 0);
            }
        __syncthreads();   // (3) all QK reads of K done; KsPt becomes P^T bounce

        if (tb + 63 > Q0) {            // boundary tile (wave-uniform branch)
            int qg = Q0 + l16;
#pragma unroll
            for (int j = 0; j < 4; j++)
#pragma unroll
                for (int r = 0; r < 4; r++) {
                    int kvg = tb + j * 16 + quad * 4 + r;
                    if (kvg > qg) sc[j][r] = -3.0e38f;
                }
        }
        float mx = -3.0e38f;
#pragma unroll
        for (int j = 0; j < 4; j++)
#pragma unroll
            for (int r = 0; r < 4; r++) mx = fmaxf(mx, sc[j][r]);
        mx = fmaxf(mx, __shfl_xor(mx, 16));
        mx = fmaxf(mx, __shfl_xor(mx, 32));
        float mnew  = fmaxf(mr, mx);
        float alpha = fast_exp2(mr - mnew);
        float ps = 0.f;
#pragma unroll
        for (int j = 0; j < 4; j++) {
            ushort4 pk;
            float p0 = fast_exp2(sc[j][0] - mnew);
            float p1 = fast_exp2(sc[j][1] - mnew);
            float p2 = fast_exp2(sc[j][2] - mnew);
            float p3 = fast_exp2(sc[j][3] - mnew);
            ps += (p0 + p1) + (p2 + p3);
            pk.x = f2bf(p0); pk.y = f2bf(p1); pk.z = f2bf(p2); pk.w = f2bf(p3);
            *(ushort4*)&PtW[l16 * 72 + j * 16 + quad * 4] = pk;
        }
        ps += __shfl_xor(ps, 16);
        ps += __shfl_xor(ps, 32);
        ls = ls * alpha + ps;
        mr = mnew;
#pragma unroll
        for (int n = 0; n < 8; n++) Ot[n] *= alpha;
        __threadfence_block();   // wave-private P^T writes -> reads

#pragma unroll
        for (int h2 = 0; h2 < 2; h2++) {
            bf16x8 pf = *(const bf16x8*)&PtW[l16 * 72 + h2 * 32 + quad * 8];
#pragma unroll
            for (int n = 0; n < 8; n++) {
                bf16x8 vf = *(const bf16x8*)&Vs2[h2][n * 16 + l16][quad * 8];
                Ot[n] = __builtin_amdgcn_mfma_f32_16x16x32_bf16(vf, pf, Ot[n], 0, 0, 0);
            }
        }
    }

    // epilogue: transpose O^T (d-major) -> O rows via own wave's PtW slice, 16B stores
    long slot = (long)bh * SLOTS_PER_BH_ + 4 * S + wave * nc + c;
#pragma unroll
    for (int half = 0; half < 2; half++) {
        __threadfence_block();
#pragma unroll
        for (int n2 = 0; n2 < 4; n2++) {
            int n = half * 4 + n2;
            ushort4 pk;
            pk.x = f2bf(Ot[n][0]); pk.y = f2bf(Ot[n][1]);
            pk.z = f2bf(Ot[n][2]); pk.w = f2bf(Ot[n][3]);
            *(ushort4*)&PtW[l16 * 72 + n2 * 16 + quad * 4] = pk;
        }
        __threadfence_block();
#pragma unroll
        for (int rr = 0; rr < 2; rr++) {
            int qrow = rr * 8 + (lane >> 3);
            int colseg = (lane & 7) * 8;
            uint4 val = *(const uint4*)&PtW[qrow * 72 + colseg];
            *(uint4*)&po[slot * 2048 + qrow * 128 + half * 64 + colseg] = val;
        }
    }
    if (lane < 16) {
        pm[slot * 16 + lane] = mr;
        pl[slot * 16 + lane] = ls;
    }
}

// ---------------------------------------------------------------- split-K combine -> Y (B,T,DIM) bf16
__global__ __launch_bounds__(256) void attn_combine(const unsigned short* __restrict__ po,
                                                    const float* __restrict__ pm,
                                                    const float* __restrict__ pl,
                                                    unsigned short* __restrict__ Y) {
    int bh = blockIdx.x >> 7, i2 = blockIdx.x & 127;   // i2 = 16-row group
    int qb = i2 >> 2, w = i2 & 3;
    int a = qb / 6, bb = qb % 6;
    int S = qb + 3 * a * (a - 1) + a * bb;             // chunks before qb
    int nc = a + 1;
    long slot0 = (long)bh * SLOTS_PER_BH_ + 4 * S + w * nc;
    int col = threadIdx.x & 127;
    int r0  = threadIdx.x >> 7;
    int b = bh >> 4, h = bh & 15;
    for (int r = r0; r < 16; r += 2) {
        float M = -3.0e38f;
        for (int c = 0; c < nc; c++) M = fmaxf(M, pm[(slot0 + c) * 16 + r]);
        float L = 0.f, acc = 0.f;
        for (int c = 0; c < nc; c++) {
            float wgt = fast_exp2(pm[(slot0 + c) * 16 + r] - M);
            L   += pl[(slot0 + c) * 16 + r] * wgt;
            acc += wgt * bf2f(po[(slot0 + c) * 2048 + r * 128 + col]);
        }
        Y[((long)b * T_ + i2 * 16 + r) * DIM_ + h * 128 + col] = f2bf(acc / L);
    }
}

// ---------------------------------------------------------------- launch
extern "C" void kernel_launch(void* const* d_in, const int* in_sizes, int n_in,
                              void* d_out, int out_size, void* d_ws, size_t ws_size,
                              hipStream_t stream) {
    const float* x     = (const float*)d_in[0];
    const float* Wq    = (const float*)d_in[1];
    const float* Wdown = (const float*)d_in[2];
    const float* Wkup  = (const float*)d_in[3];
    const float* Wvup  = (const float*)d_in[4];
    const float* Wproj = (const float*)d_in[5];
    const float* qgain = (const float*)d_in[6];

    char* ws = (char*)d_ws;
    size_t off = 0;
    auto alloc = [&](size_t bytes) -> void* {
        void* p = ws + off;
        off += (bytes + 255) & ~(size_t)255;
        return p;
    };
    // region 1: live through the whole pipeline
    unsigned short* Wp_bf  = (unsigned short*)alloc((size_t)DIM_ * DIM_ * 2);
    unsigned short* q_bf   = (unsigned short*)alloc((size_t)BT_ * DIM_ * 2);
    unsigned short* k_bf   = (unsigned short*)alloc((size_t)B_ * NKV_ * T_ * 128 * 2);
    unsigned short* vT_bf  = (unsigned short*)alloc((size_t)B_ * NKV_ * T_ * 128 * 2);
    unsigned short* y_bf   = (unsigned short*)alloc((size_t)BT_ * DIM_ * 2);
    // region 2: dead before attn -> overlaid by split-K partials
    char* region2 = ws + off;
    unsigned short* x_bf   = (unsigned short*)alloc((size_t)BT_ * DIM_ * 2);
    unsigned short* Wqd_bf = (unsigned short*)alloc((size_t)2560 * DIM_ * 2);   // [Wq;Wdown]
    unsigned short* Wkv_bf = (unsigned short*)alloc((size_t)1024 * RANK_ * 2);  // [Wkup;Wvup]
    unsigned short* q_lin  = (unsigned short*)alloc((size_t)BT_ * DIM_ * 2);
    unsigned short* lat_bf = (unsigned short*)alloc((size_t)BT_ * RANK_ * 2);
    unsigned short* kv_lin = (unsigned short*)alloc((size_t)BT_ * 1024 * 2);

    // partials: 32 bh * 408 slots * (16x128 bf16 + 16 m + 16 l) = 53.5 + 0.84 + 0.84 MB <= 57.7 MB region2
    const size_t NSLOT = 32 * SLOTS_PER_BH_;
    unsigned short* po = (unsigned short*)region2;
    float* pm = (float*)(region2 + NSLOT * 2048 * 2);
    float* pl = pm + NSLOT * 16;

    // one batched cvt launch for all six f32->bf16 casts
    CvtArgs ca;
    ca.src[0] = x;     ca.dst[0] = x_bf;
    ca.src[1] = Wq;    ca.dst[1] = Wqd_bf;
    ca.src[2] = Wdown; ca.dst[2] = Wqd_bf + (size_t)DIM_ * DIM_;
    ca.src[3] = Wkup;  ca.dst[3] = Wkv_bf;
    ca.src[4] = Wvup;  ca.dst[4] = Wkv_bf + (size_t)512 * RANK_;
    ca.src[5] = Wproj; ca.dst[5] = Wp_bf;
    int n4[6] = {BT_ * DIM_ / 4, DIM_ * DIM_ / 4, RANK_ * DIM_ / 4,
                 512 * RANK_ / 4, 512 * RANK_ / 4, DIM_ * DIM_ / 4};
    int acc4 = 0;
    for (int i = 0; i < 6; i++) { ca.start4[i] = acc4; acc4 += n4[i]; }
    cvt_all<<<(acc4 + 255) / 256, 256, 0, stream>>>(ca, acc4);

    // fused [q_lin | lat] = x @ [Wq;Wdown]^T
    gemm_split<<<dim3(2560 / 128, BT_ / 128), 256, 0, stream>>>(x_bf, Wqd_bf, q_lin, DIM_, lat_bf, BT_, 2560, DIM_);
    // kv_lin = lat @ [Wkup;Wvup]^T
    gemm_bt<unsigned short><<<dim3(1024 / 128, BT_ / 128), 256, 0, stream>>>(lat_bf, Wkv_bf, kv_lin, BT_, 1024, RANK_);

    // fused q-prep + k-prep + v-transpose
    prep_all<<<16384 + 4096 + 2048, 256, 0, stream>>>(q_lin, kv_lin, qgain, q_bf, k_bf, vT_bf);

    attn_kernel<<<dim3(8 * SLOTS_PER_BH_), 256, 0, stream>>>(q_bf, k_bf, vT_bf, po, pm, pl);
    attn_combine<<<dim3(32 * 128), 256, 0, stream>>>(po, pm, pl, y_bf);

    gemm_bt<float><<<dim3(DIM_ / 128, BT_ / 128), 256, 0, stream>>>(y_bf, Wp_bf, (float*)d_out, BT_, DIM_, DIM_);
}

// Round 9
// 370.896 us; speedup vs baseline: 1.3944x; 1.0093x over previous
//
#include <hip/hip_runtime.h>
#include <stdint.h>

#define B_    2
#define T_    2048
#define NH_   16
#define NKV_  4
#define HD_   128
#define RANK_ 512
#define DIM_  2048
#define BT_   (B_*T_)
#define EPS_  1.1920928955078125e-07f
#define LOG2E_ 1.4426950408889634f
#define CT_   6              // kv-tiles per attn chunk (balanced split-K)
#define CHUNKS_ 102          // sum over qb=0..31 of ceil((qb+1)/6)
#define SLOTS_PER_BH_ 408    // 4 waves * CHUNKS_

typedef __bf16 bf16x8 __attribute__((ext_vector_type(8)));
typedef float  f32x4  __attribute__((ext_vector_type(4)));

__device__ inline unsigned short f2bf(float f) {
    unsigned int u = __float_as_uint(f);
    u += 0x7fff + ((u >> 16) & 1);   // round-to-nearest-even
    return (unsigned short)(u >> 16);
}
__device__ inline float bf2f(unsigned short u) {
    return __uint_as_float(((unsigned int)u) << 16);
}
// exp2: hardware v_exp_f32 (avoid __exp2f: glibc macro clash on this toolchain)
__device__ inline float fast_exp2(float x) { return __builtin_amdgcn_exp2f(x); }

#define GLOAD_LDS16(gp, lp)                                                        \
    __builtin_amdgcn_global_load_lds(                                              \
        (const __attribute__((address_space(1))) void*)(gp),                       \
        (__attribute__((address_space(3))) void*)(lp), 16, 0, 0)

// XOR chunk swizzle: physical 16B-chunk p in a 64B row holds logical chunk p ^ ((row>>1)&3).
// Staging reads global chunk (lane&3)^((lane>>3)&3); readers fetch position quad^((l16>>1)&3).
// Turns the 8-way b128 bank conflict (row stride 64B) into a free 2-way.

// ---------------------------------------------------------------- batched f32 -> bf16 (one launch)
struct CvtArgs {
    const float* src[6];
    unsigned short* dst[6];
    int start4[6];   // cumulative float4 offsets
};
__global__ __launch_bounds__(256) void cvt_all(CvtArgs a, int total4) {
    int i = blockIdx.x * 256 + threadIdx.x;
    if (i >= total4) return;
    int s = 0;
#pragma unroll
    for (int k = 1; k < 6; k++) s += (i >= a.start4[k]) ? 1 : 0;
    int j = i - a.start4[s];
    float4 v = ((const float4*)a.src[s])[j];
    ushort4 o;
    o.x = f2bf(v.x); o.y = f2bf(v.y); o.z = f2bf(v.z); o.w = f2bf(v.w);
    ((ushort4*)a.dst[s])[j] = o;
}

// ---------------------------------------------------------------- GEMM C = A * W^T
// m97 recipe + BK=64 + LDS chunk swizzle.
__device__ inline void store_out(float* p, float v) { *p = v; }
__device__ inline void store_out(unsigned short* p, float v) { *p = f2bf(v); }

template <typename OT>
__global__ __launch_bounds__(256) void gemm_bt(const unsigned short* __restrict__ A,
                                               const unsigned short* __restrict__ W,
                                               OT* __restrict__ C,
                                               int M, int N, int K) {
    __shared__ unsigned short As[2][128][32];
    __shared__ unsigned short Ws[2][128][32];
    int tid  = threadIdx.x;
    int lane = tid & 63, wave = tid >> 6;
    int quad = lane >> 4, l16 = lane & 15;
    int sw   = (l16 >> 1) & 3;                 // read-side swizzle
    int wm = (wave >> 1) * 64, wn = (wave & 1) * 64;
    long m0 = (long)blockIdx.y * 128, n0 = (long)blockIdx.x * 128;

    int sr  = wave * 32 + (lane >> 2);
    int scl = (((lane & 3) ^ ((lane >> 3) & 3))) * 8;   // staging-side swizzle
    const unsigned short* Ag0 = A + (m0 + sr) * K + scl;
    const unsigned short* Ag1 = A + (m0 + sr + 16) * K + scl;
    const unsigned short* Wg0 = W + (n0 + sr) * K + scl;
    const unsigned short* Wg1 = W + (n0 + sr + 16) * K + scl;
    unsigned short* Al0 = &As[0][wave * 32][0];
    unsigned short* Al1 = &As[0][wave * 32 + 16][0];
    unsigned short* Wl0 = &Ws[0][wave * 32][0];
    unsigned short* Wl1 = &Ws[0][wave * 32 + 16][0];

    f32x4 acc[4][4];
#pragma unroll
    for (int i = 0; i < 4; i++)
#pragma unroll
        for (int j = 0; j < 4; j++) acc[i][j] = (f32x4){0.f, 0.f, 0.f, 0.f};

    for (int k0 = 0; k0 < K; k0 += 64) {
        __syncthreads();
        GLOAD_LDS16(Ag0 + k0, Al0);
        GLOAD_LDS16(Ag1 + k0, Al1);
        GLOAD_LDS16(Wg0 + k0, Wl0);
        GLOAD_LDS16(Wg1 + k0, Wl1);
        GLOAD_LDS16(Ag0 + k0 + 32, Al0 + 4096);
        GLOAD_LDS16(Ag1 + k0 + 32, Al1 + 4096);
        GLOAD_LDS16(Wg0 + k0 + 32, Wl0 + 4096);
        GLOAD_LDS16(Wg1 + k0 + 32, Wl1 + 4096);
        __syncthreads();
#pragma unroll
        for (int p = 0; p < 2; p++) {
            bf16x8 af[4], wf[4];
#pragma unroll
            for (int i = 0; i < 4; i++) af[i] = *(const bf16x8*)&As[p][wm + i * 16 + l16][(quad ^ sw) * 8];
#pragma unroll
            for (int j = 0; j < 4; j++) wf[j] = *(const bf16x8*)&Ws[p][wn + j * 16 + l16][(quad ^ sw) * 8];
#pragma unroll
            for (int i = 0; i < 4; i++)
#pragma unroll
                for (int j = 0; j < 4; j++)
                    acc[i][j] = __builtin_amdgcn_mfma_f32_16x16x32_bf16(af[i], wf[j], acc[i][j], 0, 0, 0);
        }
    }
#pragma unroll
    for (int i = 0; i < 4; i++)
#pragma unroll
        for (int j = 0; j < 4; j++)
#pragma unroll
            for (int r = 0; r < 4; r++) {
                long row = m0 + wm + i * 16 + quad * 4 + r;
                long col = n0 + wn + j * 16 + l16;
                store_out(&C[row * N + col], acc[i][j][r]);
            }
}

// GEMM with split destination: block-columns < N1 -> C1 (ld N1), else C2 (ld N-N1). Both bf16.
__global__ __launch_bounds__(256) void gemm_split(const unsigned short* __restrict__ A,
                                                  const unsigned short* __restrict__ W,
                                                  unsigned short* __restrict__ C1, int N1,
                                                  unsigned short* __restrict__ C2,
                                                  int M, int N, int K) {
    __shared__ unsigned short As[2][128][32];
    __shared__ unsigned short Ws[2][128][32];
    int tid  = threadIdx.x;
    int lane = tid & 63, wave = tid >> 6;
    int quad = lane >> 4, l16 = lane & 15;
    int sw   = (l16 >> 1) & 3;
    int wm = (wave >> 1) * 64, wn = (wave & 1) * 64;
    long m0 = (long)blockIdx.y * 128, n0 = (long)blockIdx.x * 128;

    int sr  = wave * 32 + (lane >> 2);
    int scl = (((lane & 3) ^ ((lane >> 3) & 3))) * 8;
    const unsigned short* Ag0 = A + (m0 + sr) * K + scl;
    const unsigned short* Ag1 = A + (m0 + sr + 16) * K + scl;
    const unsigned short* Wg0 = W + (n0 + sr) * K + scl;
    const unsigned short* Wg1 = W + (n0 + sr + 16) * K + scl;
    unsigned short* Al0 = &As[0][wave * 32][0];
    unsigned short* Al1 = &As[0][wave * 32 + 16][0];
    unsigned short* Wl0 = &Ws[0][wave * 32][0];
    unsigned short* Wl1 = &Ws[0][wave * 32 + 16][0];

    f32x4 acc[4][4];
#pragma unroll
    for (int i = 0; i < 4; i++)
#pragma unroll
        for (int j = 0; j < 4; j++) acc[i][j] = (f32x4){0.f, 0.f, 0.f, 0.f};

    for (int k0 = 0; k0 < K; k0 += 64) {
        __syncthreads();
        GLOAD_LDS16(Ag0 + k0, Al0);
        GLOAD_LDS16(Ag1 + k0, Al1);
        GLOAD_LDS16(Wg0 + k0, Wl0);
        GLOAD_LDS16(Wg1 + k0, Wl1);
        GLOAD_LDS16(Ag0 + k0 + 32, Al0 + 4096);
        GLOAD_LDS16(Ag1 + k0 + 32, Al1 + 4096);
        GLOAD_LDS16(Wg0 + k0 + 32, Wl0 + 4096);
        GLOAD_LDS16(Wg1 + k0 + 32, Wl1 + 4096);
        __syncthreads();
#pragma unroll
        for (int p = 0; p < 2; p++) {
            bf16x8 af[4], wf[4];
#pragma unroll
            for (int i = 0; i < 4; i++) af[i] = *(const bf16x8*)&As[p][wm + i * 16 + l16][(quad ^ sw) * 8];
#pragma unroll
            for (int j = 0; j < 4; j++) wf[j] = *(const bf16x8*)&Ws[p][wn + j * 16 + l16][(quad ^ sw) * 8];
#pragma unroll
            for (int i = 0; i < 4; i++)
#pragma unroll
                for (int j = 0; j < 4; j++)
                    acc[i][j] = __builtin_amdgcn_mfma_f32_16x16x32_bf16(af[i], wf[j], acc[i][j], 0, 0, 0);
        }
    }
    unsigned short* Cb;
    long ldc, nb;
    if (n0 < N1) { Cb = C1; ldc = N1;     nb = n0; }
    else         { Cb = C2; ldc = N - N1; nb = n0 - N1; }
#pragma unroll
    for (int i = 0; i < 4; i++)
#pragma unroll
        for (int j = 0; j < 4; j++)
#pragma unroll
            for (int r = 0; r < 4; r++) {
                long row = m0 + wm + i * 16 + quad * 4 + r;
                long col = nb + wn + j * 16 + l16;
                Cb[row * ldc + col] = f2bf(acc[i][j][r]);
            }
}

// ---------------------------------------------------------------- fused prep: q RMS+RoPE+gain | k RMS+RoPE | V transpose
__global__ __launch_bounds__(256) void prep_all(const unsigned short* __restrict__ q_lin,
                                                const unsigned short* __restrict__ kv_lin,
                                                const float* __restrict__ gain,
                                                unsigned short* __restrict__ q_bf,
                                                unsigned short* __restrict__ k_bf,
                                                unsigned short* __restrict__ vt) {
    int bid = blockIdx.x;
    if (bid < 20480) {      // q-prep (16384) + k-prep (4096)
        bool isQ = bid < 16384;
        int nheads = isQ ? NH_ : NKV_;
        int incols = isQ ? DIM_ : 1024;
        const unsigned short* lin = isQ ? q_lin : kv_lin;
        unsigned short* out = isQ ? q_bf : k_bf;
        int base = isQ ? bid : bid - 16384;
        int r    = base * 4 + (threadIdx.x >> 6);
        int lane = threadIdx.x & 63;
        int bt = r / nheads, h = r % nheads;
        const unsigned short* ip = lin + (long)bt * incols + h * 128;
        float x1 = bf2f(ip[lane]), x2 = bf2f(ip[lane + 64]);
        float ss = x1 * x1 + x2 * x2;
#pragma unroll
        for (int off = 32; off; off >>= 1) ss += __shfl_xor(ss, off);
        float inv = rsqrtf(ss * (1.0f / 128.0f) + EPS_);
        x1 *= inv; x2 *= inv;
        int b = bt / T_, t = bt % T_;
        float freq = expf(-(float)lane * 0.14391156463f);   // ln(10000)/64
        float f = (float)t * freq;
        float s, c;
        sincosf(f, &s, &c);
        float g = isQ ? gain[h] * 0.08838834764831845f * LOG2E_ : 1.0f;  // fold scale*log2e into Q
        float o1 = (x1 * c + x2 * s) * g;
        float o2 = (x2 * c - x1 * s) * g;
        unsigned short* op = out + ((long)(b * nheads + h) * T_ + t) * 128;
        op[lane]      = f2bf(o1);
        op[lane + 64] = f2bf(o2);
    } else {                // V transpose: kv_lin cols 512..1023 -> (B,NKV,128,T)
        __shared__ unsigned short tile[32][33];
        int idx = bid - 20480;          // [0,2048)
        int tt = idx & 63, dd = (idx >> 6) & 3, bkv = idx >> 8;
        int b = bkv >> 2, kv = bkv & 3;
        int t0 = tt * 32, d0 = dd * 32;
        int tx = threadIdx.x & 31, ty = threadIdx.x >> 5;
#pragma unroll
        for (int rr = 0; rr < 32; rr += 8) {
            int t = t0 + ty + rr;
            tile[ty + rr][tx] = kv_lin[((long)(b * T_ + t)) * 1024 + 512 + kv * 128 + d0 + tx];
        }
        __syncthreads();
#pragma unroll
        for (int rr = 0; rr < 32; rr += 8) {
            int d = d0 + ty + rr;
            vt[((long)((b * NKV_ + kv) * 128 + d)) * T_ + t0 + tx] = tile[tx][ty + rr];
        }
    }
}

// ---------------------------------------------------------------- flash attention (u=1: 16 q-rows/wave)
// Block = (b,kv,h',qb,c): 64 q rows, chunk of up to CT_=6 kv-tiles. XCD swizzle blockIdx%8=(b*4+kv).
// nc(qb)=qb/6+1, 102 chunks per bh-head -> 3264 blocks, longest-first.
// LDS 32KB: Vs 16KB + KsPt 16KB (K during QK / wave-private P^T [16][72] after barrier(3)).
// K/V LDS images chunk-XOR swizzled (8-way -> 2-way bank conflicts).
// __launch_bounds__(256,4): u=1 fits the 128-reg budget (u=2 spilled - R5).
__global__ __launch_bounds__(256, 4) void attn_kernel(const unsigned short* __restrict__ Q,
                                                      const unsigned short* __restrict__ Km,
                                                      const unsigned short* __restrict__ Vt,
                                                      unsigned short* __restrict__ po,
                                                      float* __restrict__ pm,
                                                      float* __restrict__ pl) {
    __shared__ alignas(16) unsigned short Vs2[2][128][32];   // [kv-chunk][d][kv in chunk]
    __shared__ alignas(16) unsigned short KsPt[4 * 64 * 32]; // K [4][64][32] / P^T [4][16][72]

    int tid = threadIdx.x, lane = tid & 63, wave = tid >> 6;
    int quad = lane >> 4, l16 = lane & 15;
    int sw   = (l16 >> 1) & 3;                           // read-side swizzle
    int csw  = ((lane & 3) ^ ((lane >> 3) & 3));         // staging-side swizzle

    int g8 = blockIdx.x & 7;          // XCD slot = (b*4+kv)
    int j5 = blockIdx.x >> 3;         // [0, 408) = 4 heads x 102 chunks
    int hh = j5 / CHUNKS_;
    int rem = (CHUNKS_ - 1) - (j5 % CHUNKS_);   // longest-first
    int b = g8 >> 2, kvh = g8 & 3, h = kvh * 4 + hh, bh = b * 16 + h;
    // decode rem -> (qb in [0,32), c): nc(qb) = qb/6+1, S = chunks before qb
    int qb = 0, S = 0;
    while (S + (qb / 6 + 1) <= rem) { S += qb / 6 + 1; ++qb; }
    int nc = qb / 6 + 1;
    int c  = rem - S;
    int Q0 = qb * 64 + wave * 16;

    int kt0 = c * CT_;
    int nt  = min(CT_, qb + 1 - kt0);

    const unsigned short* qp = Q + ((long)(b * NH_ + h) * T_ + Q0) * 128;
    const char* kb = (const char*)(Km + (long)(b * NKV_ + kvh) * T_ * 128);
    const char* vb = (const char*)(Vt + (long)(b * NKV_ + kvh) * 128 * (long)T_);
    char* ksB = (char*)&KsPt[0];
    char* vsB = (char*)&Vs2[0][0][0];
    unsigned short* PtW = &KsPt[wave * 1152];   // [16][72] per wave

    bf16x8 Qf[4];
#pragma unroll
    for (int s = 0; s < 4; s++)
        Qf[s] = *(const bf16x8*)&qp[l16 * 128 + s * 32 + quad * 8];

    f32x4 Ot[8];
#pragma unroll
    for (int n = 0; n < 8; n++) Ot[n] = (f32x4){0.f, 0.f, 0.f, 0.f};
    float mr = -3.0e38f, ls = 0.f;

    for (int kt = kt0; kt < kt0 + nt; kt++) {
        int tb = kt * 64;
        __syncthreads();   // (1) prior tile's P/V reads done before restaging
        {   // stage K: wave = d-chunk s; source chunk index swizzled
            const char* kg = kb + (long)tb * 256 + wave * 64 + (lane >> 2) * 256 + csw * 16;
            char* kl = ksB + wave * 4096 + lane * 16;
#pragma unroll
            for (int r = 0; r < 4; r++)
                GLOAD_LDS16(kg + r * 4096, kl + r * 1024);
        }
        {   // stage V (source chunk index swizzled)
            int h2 = wave >> 1;
            int D0 = (wave & 1) * 64;
#pragma unroll
            for (int r = 0; r < 4; r++) {
                int D = D0 + r * 16;
                const char* vgr = vb + (long)(D + (lane >> 2)) * 4096 + (long)tb * 2 + h2 * 64 + csw * 16;
                char* vl = vsB + h2 * 8192 + D * 64 + lane * 16;
                GLOAD_LDS16(vgr, vl);
            }
        }
        __syncthreads();   // (2) staged data visible

        f32x4 sc[4];
#pragma unroll
        for (int j = 0; j < 4; j++) sc[j] = (f32x4){0.f, 0.f, 0.f, 0.f};
#pragma unroll
        for (int j = 0; j < 4; j++)
#pragma unroll
            for (int s = 0; s < 4; s++) {
                bf16x8 kf = *(const bf16x8*)&KsPt[s * 2048 + (j * 16 + l16) * 32 + ((s ^ 0) == s ? (quad ^ sw) : (quad ^ sw)) * 8];
                sc[j] = __builtin_amdgcn_mfma_f32_16x16x32_bf16(kf, Qf[s], sc[j], 0, 0, 0);
            }
        __syncthreads();   // (3) all QK reads of K done; KsPt becomes P^T bounce

        if (tb + 63 > Q0) {            // boundary tile (wave-uniform branch)
            int qg = Q0 + l16;
#pragma unroll
            for (int j = 0; j < 4; j++)
#pragma unroll
                for (int r = 0; r < 4; r++) {
                    int kvg = tb + j * 16 + quad * 4 + r;
                    if (kvg > qg) sc[j][r] = -3.0e38f;
                }
        }
        float mx = -3.0e38f;
#pragma unroll
        for (int j = 0; j < 4; j++)
#pragma unroll
            for (int r = 0; r < 4; r++) mx = fmaxf(mx, sc[j][r]);
        mx = fmaxf(mx, __shfl_xor(mx, 16));
        mx = fmaxf(mx, __shfl_xor(mx, 32));
        float mnew  = fmaxf(mr, mx);
        float alpha = fast_exp2(mr - mnew);
        float ps = 0.f;
#pragma unroll
        for (int j = 0; j < 4; j++) {
            ushort4 pk;
            float p0 = fast_exp2(sc[j][0] - mnew);
            float p1 = fast_exp2(sc[j][1] - mnew);
            float p2 = fast_exp2(sc[j][2] - mnew);
            float p3 = fast_exp2(sc[j][3] - mnew);
            ps += (p0 + p1) + (p2 + p3);
            pk.x = f2bf(p0); pk.y = f2bf(p1); pk.z = f2bf(p2); pk.w = f2bf(p3);
            *(ushort4*)&PtW[l16 * 72 + j * 16 + quad * 4] = pk;
        }
        ps += __shfl_xor(ps, 16);
        ps += __shfl_xor(ps, 32);
        ls = ls * alpha + ps;
        mr = mnew;
#pragma unroll
        for (int n = 0; n < 8; n++) Ot[n] *= alpha;
        __threadfence_block();   // wave-private P^T writes -> reads

#pragma unroll
        for (int h2 = 0; h2 < 2; h2++) {
            bf16x8 pf = *(const bf16x8*)&PtW[l16 * 72 + h2 * 32 + quad * 8];
#pragma unroll
            for (int n = 0; n < 8; n++) {
                bf16x8 vf = *(const bf16x8*)&Vs2[h2][n * 16 + l16][(quad ^ sw) * 8];
                Ot[n] = __builtin_amdgcn_mfma_f32_16x16x32_bf16(vf, pf, Ot[n], 0, 0, 0);
            }
        }
    }

    // epilogue: transpose O^T (d-major) -> O rows via own wave's PtW slice, 16B stores
    long slot = (long)bh * SLOTS_PER_BH_ + 4 * S + wave * nc + c;
#pragma unroll
    for (int half = 0; half < 2; half++) {
        __threadfence_block();
#pragma unroll
        for (int n2 = 0; n2 < 4; n2++) {
            int n = half * 4 + n2;
            ushort4 pk;
            pk.x = f2bf(Ot[n][0]); pk.y = f2bf(Ot[n][1]);
            pk.z = f2bf(Ot[n][2]); pk.w = f2bf(Ot[n][3]);
            *(ushort4*)&PtW[l16 * 72 + n2 * 16 + quad * 4] = pk;
        }
        __threadfence_block();
#pragma unroll
        for (int rr = 0; rr < 2; rr++) {
            int qrow = rr * 8 + (lane >> 3);
            int colseg = (lane & 7) * 8;
            uint4 val = *(const uint4*)&PtW[qrow * 72 + colseg];
            *(uint4*)&po[slot * 2048 + qrow * 128 + half * 64 + colseg] = val;
        }
    }
    if (lane < 16) {
        pm[slot * 16 + lane] = mr;
        pl[slot * 16 + lane] = ls;
    }
}

// ---------------------------------------------------------------- split-K combine -> Y (B,T,DIM) bf16
__global__ __launch_bounds__(256) void attn_combine(const unsigned short* __restrict__ po,
                                                    const float* __restrict__ pm,
                                                    const float* __restrict__ pl,
                                                    unsigned short* __restrict__ Y) {
    int bh = blockIdx.x >> 7, i2 = blockIdx.x & 127;   // i2 = 16-row group
    int qb = i2 >> 2, w = i2 & 3;
    int a = qb / 6, bb = qb % 6;
    int S = qb + 3 * a * (a - 1) + a * bb;             // chunks before qb
    int nc = a + 1;
    long slot0 = (long)bh * SLOTS_PER_BH_ + 4 * S + w * nc;
    int col = threadIdx.x & 127;
    int r0  = threadIdx.x >> 7;
    int b = bh >> 4, h = bh & 15;
    for (int r = r0; r < 16; r += 2) {
        float M = -3.0e38f;
        for (int c = 0; c < nc; c++) M = fmaxf(M, pm[(slot0 + c) * 16 + r]);
        float L = 0.f, acc = 0.f;
        for (int c = 0; c < nc; c++) {
            float wgt = fast_exp2(pm[(slot0 + c) * 16 + r] - M);
            L   += pl[(slot0 + c) * 16 + r] * wgt;
            acc += wgt * bf2f(po[(slot0 + c) * 2048 + r * 128 + col]);
        }
        Y[((long)b * T_ + i2 * 16 + r) * DIM_ + h * 128 + col] = f2bf(acc / L);
    }
}

// ---------------------------------------------------------------- launch
extern "C" void kernel_launch(void* const* d_in, const int* in_sizes, int n_in,
                              void* d_out, int out_size, void* d_ws, size_t ws_size,
                              hipStream_t stream) {
    const float* x     = (const float*)d_in[0];
    const float* Wq    = (const float*)d_in[1];
    const float* Wdown = (const float*)d_in[2];
    const float* Wkup  = (const float*)d_in[3];
    const float* Wvup  = (const float*)d_in[4];
    const float* Wproj = (const float*)d_in[5];
    const float* qgain = (const float*)d_in[6];

    char* ws = (char*)d_ws;
    size_t off = 0;
    auto alloc = [&](size_t bytes) -> void* {
        void* p = ws + off;
        off += (bytes + 255) & ~(size_t)255;
        return p;
    };
    // region 1: live through the whole pipeline
    unsigned short* Wp_bf  = (unsigned short*)alloc((size_t)DIM_ * DIM_ * 2);
    unsigned short* q_bf   = (unsigned short*)alloc((size_t)BT_ * DIM_ * 2);
    unsigned short* k_bf   = (unsigned short*)alloc((size_t)B_ * NKV_ * T_ * 128 * 2);
    unsigned short* vT_bf  = (unsigned short*)alloc((size_t)B_ * NKV_ * T_ * 128 * 2);
    unsigned short* y_bf   = (unsigned short*)alloc((size_t)BT_ * DIM_ * 2);
    // region 2: dead before attn -> overlaid by split-K partials
    char* region2 = ws + off;
    unsigned short* x_bf   = (unsigned short*)alloc((size_t)BT_ * DIM_ * 2);
    unsigned short* Wqd_bf = (unsigned short*)alloc((size_t)2560 * DIM_ * 2);   // [Wq;Wdown]
    unsigned short* Wkv_bf = (unsigned short*)alloc((size_t)1024 * RANK_ * 2);  // [Wkup;Wvup]
    unsigned short* q_lin  = (unsigned short*)alloc((size_t)BT_ * DIM_ * 2);
    unsigned short* lat_bf = (unsigned short*)alloc((size_t)BT_ * RANK_ * 2);
    unsigned short* kv_lin = (unsigned short*)alloc((size_t)BT_ * 1024 * 2);

    // partials: 32 bh * 408 slots * (16x128 bf16 + 16 m + 16 l) = 53.5 + 0.84 + 0.84 MB <= 57.7 MB region2
    const size_t NSLOT = 32 * SLOTS_PER_BH_;
    unsigned short* po = (unsigned short*)region2;
    float* pm = (float*)(region2 + NSLOT * 2048 * 2);
    float* pl = pm + NSLOT * 16;

    // one batched cvt launch for all six f32->bf16 casts
    CvtArgs ca;
    ca.src[0] = x;     ca.dst[0] = x_bf;
    ca.src[1] = Wq;    ca.dst[1] = Wqd_bf;
    ca.src[2] = Wdown; ca.dst[2] = Wqd_bf + (size_t)DIM_ * DIM_;
    ca.src[3] = Wkup;  ca.dst[3] = Wkv_bf;
    ca.src[4] = Wvup;  ca.dst[4] = Wkv_bf + (size_t)512 * RANK_;
    ca.src[5] = Wproj; ca.dst[5] = Wp_bf;
    int n4[6] = {BT_ * DIM_ / 4, DIM_ * DIM_ / 4, RANK_ * DIM_ / 4,
                 512 * RANK_ / 4, 512 * RANK_ / 4, DIM_ * DIM_ / 4};
    int acc4 = 0;
    for (int i = 0; i < 6; i++) { ca.start4[i] = acc4; acc4 += n4[i]; }
    cvt_all<<<(acc4 + 255) / 256, 256, 0, stream>>>(ca, acc4);

    // fused [q_lin | lat] = x @ [Wq;Wdown]^T
    gemm_split<<<dim3(2560 / 128, BT_ / 128), 256, 0, stream>>>(x_bf, Wqd_bf, q_lin, DIM_, lat_bf, BT_, 2560, DIM_);
    // kv_lin = lat @ [Wkup;Wvup]^T
    gemm_bt<unsigned short><<<dim3(1024 / 128, BT_ / 128), 256, 0, stream>>>(lat_bf, Wkv_bf, kv_lin, BT_, 1024, RANK_);

    // fused q-prep + k-prep + v-transpose
    prep_all<<<16384 + 4096 + 2048, 256, 0, stream>>>(q_lin, kv_lin, qgain, q_bf, k_bf, vT_bf);

    attn_kernel<<<dim3(8 * SLOTS_PER_BH_), 256, 0, stream>>>(q_bf, k_bf, vT_bf, po, pm, pl);
    attn_combine<<<dim3(32 * 128), 256, 0, stream>>>(po, pm, pl, y_bf);

    gemm_bt<float><<<dim3(DIM_ / 128, BT_ / 128), 256, 0, stream>>>(y_bf, Wp_bf, (float*)d_out, BT_, DIM_, DIM_);
}